// Round 20
// baseline (535.847 us; speedup 1.0000x reference)
//
#include <hip/hip_runtime.h>
#include <hip/hip_bf16.h>

#define HID 128
#define OUTD 64
#define FMDIM 404
#define NB 64

using bf16x8 = __attribute__((ext_vector_type(8))) short;   // 8 bf16 in 4 VGPRs
using f32x4  = __attribute__((ext_vector_type(4))) float;
using u16x8  = __attribute__((ext_vector_type(8))) unsigned short;

#define QSCALE 65536.f
#define QINV   (1.f / 65536.f)

static __device__ __forceinline__ short f2b(float f) {
    __hip_bfloat16 h = __float2bfloat16(f);          // RNE
    return *reinterpret_cast<short*>(&h);
}
static __device__ __forceinline__ float b2f(unsigned short u) {
    return __uint_as_float(((unsigned)u) << 16);
}
// fixed-point quantize for order-independent (associative) gather sums
static __device__ __forceinline__ int q16(unsigned short u) {
    return __float2int_rn(b2f(u) * QSCALE);
}

// guarded float4 load: address always in-bounds, value zero when k0+4 > Kin (Kin % 4 == 0)
static __device__ __forceinline__ float4 ld4_guard(const float* rowp, int k0, int Kin) {
    bool ok = (k0 + 4 <= Kin);
    const float4* p = reinterpret_cast<const float4*>(rowp + (ok ? k0 : 0));
    float4 v = *p;
    return ok ? v : float4{0.f, 0.f, 0.f, 0.f};
}

static __device__ __forceinline__ bf16x8 ldcvt8(const float* rowp, int k0, int Kin) {
    float4 f0 = ld4_guard(rowp, k0, Kin);
    float4 f1 = ld4_guard(rowp, k0 + 4, Kin);
    bf16x8 r;
    r[0] = f2b(f0.x); r[1] = f2b(f0.y); r[2] = f2b(f0.z); r[3] = f2b(f0.w);
    r[4] = f2b(f1.x); r[5] = f2b(f1.y); r[6] = f2b(f1.z); r[7] = f2b(f1.w);
    return r;
}

// ======================= weight repack: f32 W[K][N] -> bf16 frag layout =======================
__global__ void repack_w_kernel(const float* __restrict__ W, short* __restrict__ out,
                                int K, int N, int KT)
{
    int idx = blockIdx.x * blockDim.x + threadIdx.x;
    int total = (N >> 4) * KT * 512;
    if (idx >= total) return;
    int j    = idx & 7;
    int lane = (idx >> 3) & 63;
    int grp  = idx >> 9;
    int kk   = grp % KT, nt = grp / KT;
    int k    = kk * 32 + (lane >> 4) * 8 + j;
    int col  = nt * 16 + (lane & 15);
    out[idx] = (k < K) ? f2b(W[(size_t)k * N + col]) : (short)0;
}

// ======================= encoder MFMA: f32 in, relu->LN, bf16 table out =======================
template<int NT, int KT>
__global__ __launch_bounds__(256) void enc_mfma_kernel(
    const float* __restrict__ A1, int Kin1,
    const bf16x8* __restrict__ W1,
    const float* __restrict__ bias, const float* __restrict__ g, const float* __restrict__ beta,
    short* __restrict__ outB, int mtiles)
{
    constexpr int N = NT * 16;
    const int lane = threadIdx.x & 63;
    const int wave = threadIdx.x >> 6;
    const int t = blockIdx.x * 4 + wave;
    if (t >= mtiles) return;

    const int lr = lane & 15;
    const int lk = lane >> 4;
    const int row = t * 16 + lr;
    const float* a1p = A1 + (size_t)row * Kin1;

    f32x4 acc[NT];
#pragma unroll
    for (int n = 0; n < NT; ++n) acc[n] = f32x4{0.f, 0.f, 0.f, 0.f};

#pragma unroll
    for (int kk = 0; kk < KT; ++kk) {
        const int k0 = kk * 32 + lk * 8;
        bf16x8 a1 = ldcvt8(a1p, k0, Kin1);
#pragma unroll
        for (int n = 0; n < NT; ++n) {
            bf16x8 b1 = W1[(size_t)(n * KT + kk) * 64 + lane];
            acc[n] = __builtin_amdgcn_mfma_f32_16x16x32_bf16(a1, b1, acc[n], 0, 0, 0);
        }
    }

    const int rowbase = t * 16;
    float v[NT][4];
#pragma unroll
    for (int n = 0; n < NT; ++n) {
        const float bc = bias[n * 16 + lr];
#pragma unroll
        for (int q = 0; q < 4; ++q) v[n][q] = fmaxf(acc[n][q] + bc, 0.f);
    }
    float gcol[NT], becol[NT];
#pragma unroll
    for (int n = 0; n < NT; ++n) { gcol[n] = g[n * 16 + lr]; becol[n] = beta[n * 16 + lr]; }
#pragma unroll
    for (int q = 0; q < 4; ++q) {
        float s = 0.f, ss = 0.f;
#pragma unroll
        for (int n = 0; n < NT; ++n) { s += v[n][q]; ss += v[n][q] * v[n][q]; }
#pragma unroll
        for (int m = 1; m < 16; m <<= 1) {
            s  += __shfl_xor(s, m);
            ss += __shfl_xor(ss, m);
        }
        const float mu   = s * (1.f / N);
        const float rstd = rsqrtf(ss * (1.f / N) - mu * mu + 1e-5f);
#pragma unroll
        for (int n = 0; n < NT; ++n) {
            float o = (v[n][q] - mu) * rstd * gcol[n] + becol[n];
            outB[(size_t)(rowbase + lk * 4 + q) * N + n * 16 + lr] = f2b(o);
        }
    }
}

// ======================= sage1 fused: int-sum gather + dual MFMA + LN->relu, bf16 out =======================
__global__ __launch_bounds__(256) void sage1_fused_kernel(
    const unsigned short* __restrict__ gfeat,
    const int* __restrict__ rowptr, int rowbase, const int* __restrict__ nbr,
    const bf16x8* __restrict__ A2b,
    const bf16x8* __restrict__ W1, const bf16x8* __restrict__ W2,
    const float* __restrict__ bias, const float* __restrict__ g, const float* __restrict__ beta,
    short* __restrict__ out, int mtiles)
{
    constexpr int NT = 8, KT = 4, N = 128;
    const int lane = threadIdx.x & 63;
    const int wave = threadIdx.x >> 6;
    const int t = blockIdx.x * 4 + wave;
    if (t >= mtiles) return;

    const int lr = lane & 15;
    const int lk = lane >> 4;
    const int row = t * 16 + lr;

    const int beg = rowptr[rowbase + row];
    const int end = rowptr[rowbase + row + 1];
    int iacc[KT][8];
#pragma unroll
    for (int kk = 0; kk < KT; ++kk)
#pragma unroll
        for (int j = 0; j < 8; ++j) iacc[kk][j] = 0;

    for (int i = beg; i < end; ++i) {
        const int nb = nbr[i];
        const u16x8* rp = reinterpret_cast<const u16x8*>(gfeat + (size_t)nb * 128);
#pragma unroll
        for (int kk = 0; kk < KT; ++kk) {
            u16x8 vv = rp[kk * 4 + lk];
#pragma unroll
            for (int j = 0; j < 8; ++j) iacc[kk][j] += q16(vv[j]);
        }
    }
    const int cnt = end - beg;
    const float sc = ((cnt > 0) ? (1.f / (float)cnt) : 0.f) * QINV;
    bf16x8 a1f[KT];
#pragma unroll
    for (int kk = 0; kk < KT; ++kk)
#pragma unroll
        for (int j = 0; j < 8; ++j) a1f[kk][j] = f2b((float)iacc[kk][j] * sc);

    f32x4 acc[NT];
#pragma unroll
    for (int n = 0; n < NT; ++n) acc[n] = f32x4{0.f, 0.f, 0.f, 0.f};
#pragma unroll
    for (int kk = 0; kk < KT; ++kk) {
        bf16x8 a2 = A2b[(size_t)row * (KT * 4) + kk * 4 + lk];
#pragma unroll
        for (int n = 0; n < NT; ++n) {
            bf16x8 b1 = W1[(size_t)(n * KT + kk) * 64 + lane];
            acc[n] = __builtin_amdgcn_mfma_f32_16x16x32_bf16(a1f[kk], b1, acc[n], 0, 0, 0);
            bf16x8 b2 = W2[(size_t)(n * KT + kk) * 64 + lane];
            acc[n] = __builtin_amdgcn_mfma_f32_16x16x32_bf16(a2, b2, acc[n], 0, 0, 0);
        }
    }

    const int rowbase2 = t * 16;
    float v[NT][4];
#pragma unroll
    for (int n = 0; n < NT; ++n) {
        const float bc = bias[n * 16 + lr];
#pragma unroll
        for (int q = 0; q < 4; ++q) v[n][q] = acc[n][q] + bc;
    }
    float gcol[NT], becol[NT];
#pragma unroll
    for (int n = 0; n < NT; ++n) { gcol[n] = g[n * 16 + lr]; becol[n] = beta[n * 16 + lr]; }
#pragma unroll
    for (int q = 0; q < 4; ++q) {
        float s = 0.f, ss = 0.f;
#pragma unroll
        for (int n = 0; n < NT; ++n) { s += v[n][q]; ss += v[n][q] * v[n][q]; }
#pragma unroll
        for (int m = 1; m < 16; m <<= 1) {
            s  += __shfl_xor(s, m);
            ss += __shfl_xor(ss, m);
        }
        const float mu   = s * (1.f / N);
        const float rstd = rsqrtf(ss * (1.f / N) - mu * mu + 1e-5f);
#pragma unroll
        for (int n = 0; n < NT; ++n) {
            float o = fmaxf((v[n][q] - mu) * rstd * gcol[n] + becol[n], 0.f);
            out[(size_t)(rowbase2 + lk * 4 + q) * N + n * 16 + lr] = f2b(o);
        }
    }
}

// ======================= CSR build =======================
__global__ void deg_csr_kernel(const int* __restrict__ src, const int* __restrict__ dst,
                               int* __restrict__ deg, int NM, int E)
{
    int e = blockIdx.x * blockDim.x + threadIdx.x;
    if (e < E) {
        atomicAdd(&deg[dst[e]], 1);
        atomicAdd(&deg[NM + src[e]], 1);
    }
}

__global__ void scan_partial_kernel(int* __restrict__ data, int* __restrict__ partials, int N)
{
    __shared__ int sh[256];
    const int tid = threadIdx.x;
    const int base = blockIdx.x * 4096 + tid * 16;
    int vals[16];
    int s = 0;
#pragma unroll
    for (int i = 0; i < 16; ++i) {
        int v = (base + i < N) ? data[base + i] : 0;
        vals[i] = s;
        s += v;
    }
    sh[tid] = s;
    __syncthreads();
    for (int off = 1; off < 256; off <<= 1) {
        int t = 0;
        if (tid >= off) t = sh[tid - off];
        __syncthreads();
        sh[tid] += t;
        __syncthreads();
    }
    int excl = (tid == 0) ? 0 : sh[tid - 1];
    if (tid == 255) partials[blockIdx.x] = sh[255];
#pragma unroll
    for (int i = 0; i < 16; ++i)
        if (base + i < N) data[base + i] = excl + vals[i];
}

__global__ void scan_add_kernel(int* __restrict__ data, const int* __restrict__ partials,
                                int N, int total, int nP)
{
    __shared__ int pref[64];
    const int tid = threadIdx.x;
    if (tid < 64) {
        int v = (tid < nP) ? partials[tid] : 0;
        for (int off = 1; off < 64; off <<= 1) {
            int t = __shfl_up(v, off);
            if (tid >= off) v += t;
        }
        pref[tid] = v;                      // inclusive prefix
    }
    __syncthreads();
    int idx = blockIdx.x * blockDim.x + tid;
    if (idx < N) {
        int p = idx >> 12;
        int excl = (p == 0) ? 0 : pref[p - 1];
        data[idx] += excl;
    }
    if (idx == 0) data[N] = total;
}

// ======================= bucketed fill (write-combining) =======================
__global__ __launch_bounds__(256) void bucket_stage_kernel(
    const int* __restrict__ src, const int* __restrict__ dst,
    const int* __restrict__ rowptr, int* __restrict__ bcur,
    int2* __restrict__ stg, int NM, int NU, int BSZ_M, int BSZ_U, int E)
{
    __shared__ int hist[2 * NB];
    __shared__ int basep[2 * NB];
    __shared__ int bbase[2 * NB];
    const int tid = threadIdx.x;
    const long e0 = (long)blockIdx.x * 2048;

    if (tid < 2 * NB) {
        hist[tid] = 0;
        if (tid < NB) bbase[tid] = rowptr[min(tid * BSZ_M, NM)];
        else          bbase[tid] = rowptr[NM + min((tid - NB) * BSZ_U, NU)];
    }
    __syncthreads();

    int es[8], ed[8];
#pragma unroll
    for (int i = 0; i < 8; ++i) {
        long e = e0 + i * 256 + tid;
        if (e < E) {
            es[i] = src[e]; ed[i] = dst[e];
            atomicAdd(&hist[ed[i] / BSZ_M], 1);
            atomicAdd(&hist[NB + es[i] / BSZ_U], 1);
        } else { es[i] = -1; ed[i] = -1; }
    }
    __syncthreads();
    if (tid < 2 * NB) {
        basep[tid] = atomicAdd(&bcur[tid], hist[tid]);
        hist[tid] = 0;                        // reuse as running in-block cursor
    }
    __syncthreads();
#pragma unroll
    for (int i = 0; i < 8; ++i) {
        if (ed[i] >= 0) {
            int b  = ed[i] / BSZ_M;
            int p  = atomicAdd(&hist[b], 1);
            stg[(long)bbase[b] + basep[b] + p] = make_int2(ed[i], es[i]);
            int b2 = es[i] / BSZ_U;
            int p2 = atomicAdd(&hist[NB + b2], 1);
            stg[(long)bbase[NB + b2] + basep[NB + b2] + p2] = make_int2(NM + es[i], ed[i]);
        }
    }
}

__global__ __launch_bounds__(256) void bucket_commit_kernel(
    const int2* __restrict__ stg, const int* __restrict__ rowptr,
    int* __restrict__ cursor, int* __restrict__ nbr,
    int NM, int NU, int BSZ_M, int BSZ_U)
{
    const int i = blockIdx.x;                 // 0 .. 2*NB-1
    int w0, w1;
    if (i < NB) {
        w0 = rowptr[min(i * BSZ_M, NM)];
        w1 = rowptr[min((i + 1) * BSZ_M, NM)];
    } else {
        int j = i - NB;
        w0 = rowptr[NM + min(j * BSZ_U, NU)];
        w1 = rowptr[NM + min((j + 1) * BSZ_U, NU)];
    }
    for (int k = w0 + (int)threadIdx.x; k < w1; k += (int)blockDim.x) {
        int2 ent = stg[k];
        int slot = rowptr[ent.x] + atomicAdd(&cursor[ent.x], 1);
        nbr[slot] = ent.y;
    }
}

// ======================= projection, dual-output =======================
// outp16     = bf16(feat16 @ wl)            (gathered by the OTHER side)
// outselfp16 = bf16(feat16 @ wr + bl)       (this side's self term for final)
template<int R>
__global__ void proj_kernel(const unsigned short* __restrict__ feat,
                            const float* __restrict__ wl, const float* __restrict__ wr,
                            const float* __restrict__ bl,
                            short* __restrict__ outp, short* __restrict__ outselfp, int n)
{
    __shared__ float4 fs[R][HID / 4];
    const int j = threadIdx.x;               // 0..63
    const int base = blockIdx.x * R;

    for (int t = j; t < R * 16; t += 64) {
        int r = t >> 4, k = t & 15;
        int row = base + r;
        if (row < n) {
            u16x8 v = *(const u16x8*)(feat + (size_t)row * HID + k * 8);
            fs[r][2 * k]     = float4{b2f(v[0]), b2f(v[1]), b2f(v[2]), b2f(v[3])};
            fs[r][2 * k + 1] = float4{b2f(v[4]), b2f(v[5]), b2f(v[6]), b2f(v[7])};
        }
    }
    __syncthreads();

    const float blj = bl[j];
    float accP[R], accS[R];
#pragma unroll
    for (int r = 0; r < R; ++r) { accP[r] = 0.f; accS[r] = blj; }

    for (int k4 = 0; k4 < 32; ++k4) {
        const float* wp = wl + (size_t)(4 * k4) * OUTD + j;
        const float* wq = wr + (size_t)(4 * k4) * OUTD + j;
        float p0 = wp[0 * OUTD], p1 = wp[1 * OUTD], p2 = wp[2 * OUTD], p3 = wp[3 * OUTD];
        float q0 = wq[0 * OUTD], q1 = wq[1 * OUTD], q2 = wq[2 * OUTD], q3 = wq[3 * OUTD];
#pragma unroll
        for (int r = 0; r < R; ++r) {
            float4 v = fs[r][k4];
            accP[r] = fmaf(v.x, p0, accP[r]);
            accP[r] = fmaf(v.y, p1, accP[r]);
            accP[r] = fmaf(v.z, p2, accP[r]);
            accP[r] = fmaf(v.w, p3, accP[r]);
            accS[r] = fmaf(v.x, q0, accS[r]);
            accS[r] = fmaf(v.y, q1, accS[r]);
            accS[r] = fmaf(v.z, q2, accS[r]);
            accS[r] = fmaf(v.w, q3, accS[r]);
        }
    }
    for (int r = 0; r < R; ++r) {
        int row = base + r;
        if (row < n) {
            outp[(size_t)row * OUTD + j]     = f2b(accP[r]);
            outselfp[(size_t)row * OUTD + j] = f2b(accS[r]);
        }
    }
}

// ======================= final fused: 8-way-ILP int-sum gather64 + LN(mean + selfp) =======================
// selfp already holds feat@wr + bl (computed in proj); no LDS, no FMA loop.
template<int R>
__global__ void final_kernel(const unsigned short* __restrict__ pfeat,
                             const int* __restrict__ rowptr, int rowbase,
                             const int* __restrict__ nbr,
                             const unsigned short* __restrict__ selfp,
                             const float* __restrict__ g, const float* __restrict__ beta,
                             float* __restrict__ out, int n)
{
    const int j = threadIdx.x;               // 0..63
    const int base = blockIdx.x * R;

    const float gv = g[j], bv = beta[j];
#pragma unroll
    for (int r = 0; r < R; ++r) {
        int row = base + r;
        float v = 0.f;
        if (row < n) {
            const int beg = rowptr[rowbase + row];
            const int end = rowptr[rowbase + row + 1];
            int s0 = 0, s1 = 0, s2 = 0, s3 = 0, s4 = 0, s5 = 0, s6 = 0, s7 = 0;
            int i = beg;
            for (; i + 7 < end; i += 8) {
                int n0 = nbr[i],     n1 = nbr[i + 1], n2 = nbr[i + 2], n3 = nbr[i + 3];
                int n4 = nbr[i + 4], n5 = nbr[i + 5], n6 = nbr[i + 6], n7 = nbr[i + 7];
                s0 += q16(pfeat[(size_t)n0 * OUTD + j]);
                s1 += q16(pfeat[(size_t)n1 * OUTD + j]);
                s2 += q16(pfeat[(size_t)n2 * OUTD + j]);
                s3 += q16(pfeat[(size_t)n3 * OUTD + j]);
                s4 += q16(pfeat[(size_t)n4 * OUTD + j]);
                s5 += q16(pfeat[(size_t)n5 * OUTD + j]);
                s6 += q16(pfeat[(size_t)n6 * OUTD + j]);
                s7 += q16(pfeat[(size_t)n7 * OUTD + j]);
            }
            for (; i + 3 < end; i += 4) {
                int n0 = nbr[i], n1 = nbr[i + 1], n2 = nbr[i + 2], n3 = nbr[i + 3];
                s0 += q16(pfeat[(size_t)n0 * OUTD + j]);
                s1 += q16(pfeat[(size_t)n1 * OUTD + j]);
                s2 += q16(pfeat[(size_t)n2 * OUTD + j]);
                s3 += q16(pfeat[(size_t)n3 * OUTD + j]);
            }
            for (; i < end; ++i)
                s0 += q16(pfeat[(size_t)nbr[i] * OUTD + j]);
            int isum = ((s0 + s1) + (s2 + s3)) + ((s4 + s5) + (s6 + s7));
            const int cnt = end - beg;
            const float sc = ((cnt > 0) ? (1.f / (float)cnt) : 0.f) * QINV;
            v = (float)isum * sc + b2f(selfp[(size_t)row * OUTD + j]);
        }
        float s = v, q = v * v;
        for (int o = 32; o > 0; o >>= 1) { s += __shfl_down(s, o); q += __shfl_down(q, o); }
        s = __shfl(s, 0); q = __shfl(q, 0);
        float mu = s * (1.f / OUTD);
        float rstd = rsqrtf(q * (1.f / OUTD) - mu * mu + 1e-5f);
        if (row < n) out[(size_t)row * OUTD + j] = (v - mu) * rstd * gv + bv;
    }
}

extern "C" void kernel_launch(void* const* d_in, const int* in_sizes, int n_in,
                              void* d_out, int out_size, void* d_ws, size_t ws_size,
                              hipStream_t stream)
{
    const float* x_user   = (const float*)d_in[0];
    const float* x_movie  = (const float*)d_in[1];
    const int*   src      = (const int*)d_in[2];
    const int*   dst      = (const int*)d_in[3];
    const float* enc_u_w  = (const float*)d_in[4];
    const float* enc_u_b  = (const float*)d_in[5];
    const float* enc_u_g  = (const float*)d_in[6];
    const float* enc_u_be = (const float*)d_in[7];
    const float* enc_m_w  = (const float*)d_in[8];
    const float* enc_m_b  = (const float*)d_in[9];
    const float* enc_m_g  = (const float*)d_in[10];
    const float* enc_m_be = (const float*)d_in[11];
    const float* c1_m_wl  = (const float*)d_in[12];
    const float* c1_m_bl  = (const float*)d_in[13];
    const float* c1_m_wr  = (const float*)d_in[14];
    const float* c1_u_wl  = (const float*)d_in[15];
    const float* c1_u_bl  = (const float*)d_in[16];
    const float* c1_u_wr  = (const float*)d_in[17];
    const float* ln1_u_g  = (const float*)d_in[18];
    const float* ln1_u_b  = (const float*)d_in[19];
    const float* ln1_m_g  = (const float*)d_in[20];
    const float* ln1_m_b  = (const float*)d_in[21];
    const float* c2_m_wl  = (const float*)d_in[22];
    const float* c2_m_bl  = (const float*)d_in[23];
    const float* c2_m_wr  = (const float*)d_in[24];
    const float* c2_u_wl  = (const float*)d_in[25];
    const float* c2_u_bl  = (const float*)d_in[26];
    const float* c2_u_wr  = (const float*)d_in[27];
    const float* ln2_u_g  = (const float*)d_in[28];
    const float* ln2_u_b  = (const float*)d_in[29];
    const float* ln2_m_g  = (const float*)d_in[30];
    const float* ln2_m_b  = (const float*)d_in[31];

    const int NU = in_sizes[0] / 16;
    const int NM = in_sizes[1] / FMDIM;
    const int E  = in_sizes[2];
    const int N  = NM + NU;
    const int BSZ_M = (NM + NB - 1) / NB;
    const int BSZ_U = (NU + NB - 1) / NB;

    // -------- workspace layout (all bf16 tables; no overlays) --------
    short* hub16   = (short*)d_ws;                      // NU*128 bf16 (enc_u out)
    short* hmb16   = hub16 + (size_t)NU * HID;          // NM*128 bf16 (enc_m out)
    short* u1b16   = hmb16 + (size_t)NM * HID;          // NU*128 bf16 (sage1_u out)
    short* m1b16   = u1b16 + (size_t)NU * HID;          // NM*128 bf16 (sage1_m out)
    short* pub16   = m1b16 + (size_t)NM * HID;          // NU*64 bf16 (proj_u gather-out)
    short* pmb16   = pub16 + (size_t)NU * OUTD;         // NM*64 bf16 (proj_m gather-out)
    short* selfpu16= pmb16 + (size_t)NM * OUTD;         // NU*64 bf16 (u1@c2_u_wr + bl)
    short* selfpm16= selfpu16 + (size_t)NU * OUTD;      // NM*64 bf16 (m1@c2_m_wr + bl)
    short* wfu   = selfpm16 + (size_t)NM * OUTD;
    short* wfm   = wfu   + 8 * 1  * 512;
    short* wf1ml = wfm   + 8 * 13 * 512;
    short* wf1mr = wf1ml + 8 * 4  * 512;
    short* wf1ul = wf1mr + 8 * 4  * 512;
    short* wf1ur = wf1ul + 8 * 4  * 512;
    int* rp      = (int*)(wf1ur + 8 * 4 * 512);
    int* cursor  = rp + (N + 1);
    int* partials= cursor + N;
    int* bcur    = partials + 64;                       // 128 bucket cursors
    int* after   = bcur + 128;
    int2* stg    = (int2*)(((uintptr_t)after + 15) & ~(uintptr_t)15);  // 2E staged pairs
    int* nbr     = (int*)(stg + (size_t)2 * E);

    float* out_u = (float*)d_out;
    float* out_m = out_u + (size_t)NU * OUTD;

    // -------- weight repacks (bf16 fragments) --------
    auto repack = [&](const float* W, short* out, int K, int Ncols, int KT) {
        int total = (Ncols >> 4) * KT * 512;
        repack_w_kernel<<<(total + 255) / 256, 256, 0, stream>>>(W, out, K, Ncols, KT);
    };
    repack(enc_u_w, wfu,   16,  128, 1);
    repack(enc_m_w, wfm,   404, 128, 13);
    repack(c1_m_wl, wf1ml, 128, 128, 4);
    repack(c1_m_wr, wf1mr, 128, 128, 4);
    repack(c1_u_wl, wf1ul, 128, 128, 4);
    repack(c1_u_wr, wf1ur, 128, 128, 4);

    // -------- CSR build (bucketed fill) --------
    hipMemsetAsync(rp, 0, (size_t)(2 * N + 1 + 64 + 128) * sizeof(int), stream);
    deg_csr_kernel<<<(E + 255) / 256, 256, 0, stream>>>(src, dst, rp, NM, E);
    {
        int nP = (N + 4095) / 4096;
        scan_partial_kernel<<<nP, 256, 0, stream>>>(rp, partials, N);
        scan_add_kernel<<<(N + 255) / 256, 256, 0, stream>>>(rp, partials, N, 2 * E, nP);
    }
    bucket_stage_kernel<<<(E + 2047) / 2048, 256, 0, stream>>>(
        src, dst, rp, bcur, stg, NM, NU, BSZ_M, BSZ_U, E);
    bucket_commit_kernel<<<2 * NB, 256, 0, stream>>>(
        stg, rp, cursor, nbr, NM, NU, BSZ_M, BSZ_U);

    const int mtU = NU / 16, mtM = NM / 16;      // 6250, 3125 (exact)
    const int gbU = (mtU + 3) / 4, gbM = (mtM + 3) / 4;

    // -------- encoders: MFMA, relu->LN, bf16 table out --------
    enc_mfma_kernel<8, 1><<<gbU, 256, 0, stream>>>(
        x_user, 16, (const bf16x8*)wfu, enc_u_b, enc_u_g, enc_u_be, hub16, mtU);
    enc_mfma_kernel<8, 13><<<gbM, 256, 0, stream>>>(
        x_movie, FMDIM, (const bf16x8*)wfm, enc_m_b, enc_m_g, enc_m_be, hmb16, mtM);

    // -------- layer-1: fused gather + dual MFMA + LN->relu, bf16 out --------
    sage1_fused_kernel<<<gbM, 256, 0, stream>>>(
        (const unsigned short*)hub16, rp, 0, nbr, (const bf16x8*)hmb16,
        (const bf16x8*)wf1ml, (const bf16x8*)wf1mr,
        c1_m_bl, ln1_m_g, ln1_m_b, m1b16, mtM);
    sage1_fused_kernel<<<gbU, 256, 0, stream>>>(
        (const unsigned short*)hmb16, rp, NM, nbr, (const bf16x8*)hub16,
        (const bf16x8*)wf1ul, (const bf16x8*)wf1ur,
        c1_u_bl, ln1_u_g, ln1_u_b, u1b16, mtU);

    // -------- layer-2 projections: dual-output (gather table + self term) --------
    proj_kernel<8><<<(NU + 7) / 8, 64, 0, stream>>>(
        (const unsigned short*)u1b16, c2_m_wl, c2_u_wr, c2_u_bl, pub16, selfpu16, NU);
    proj_kernel<8><<<(NM + 7) / 8, 64, 0, stream>>>(
        (const unsigned short*)m1b16, c2_u_wl, c2_m_wr, c2_m_bl, pmb16, selfpm16, NM);

    // -------- final: gather64 + selfp + LN -> d_out --------
    final_kernel<8><<<(NU + 7) / 8, 64, 0, stream>>>(
        (const unsigned short*)pmb16, rp, NM, nbr, (const unsigned short*)selfpu16,
        ln2_u_g, ln2_u_b, out_u, NU);
    final_kernel<8><<<(NM + 7) / 8, 64, 0, stream>>>(
        (const unsigned short*)pub16, rp, 0, nbr, (const unsigned short*)selfpm16,
        ln2_m_g, ln2_m_b, out_m, NM);
}

// Round 21
// 533.542 us; speedup vs baseline: 1.0043x; 1.0043x over previous
//
#include <hip/hip_runtime.h>
#include <hip/hip_bf16.h>

#define HID 128
#define OUTD 64
#define FMDIM 404
#define NB 64

using bf16x8 = __attribute__((ext_vector_type(8))) short;   // 8 bf16 in 4 VGPRs
using f32x4  = __attribute__((ext_vector_type(4))) float;
using u16x8  = __attribute__((ext_vector_type(8))) unsigned short;

#define QSCALE 65536.f
#define QINV   (1.f / 65536.f)

static __device__ __forceinline__ short f2b(float f) {
    __hip_bfloat16 h = __float2bfloat16(f);          // RNE
    return *reinterpret_cast<short*>(&h);
}
static __device__ __forceinline__ float b2f(unsigned short u) {
    return __uint_as_float(((unsigned)u) << 16);
}
// fixed-point quantize for order-independent (associative) gather sums
static __device__ __forceinline__ int q16(unsigned short u) {
    return __float2int_rn(b2f(u) * QSCALE);
}

// guarded float4 load: address always in-bounds, value zero when k0+4 > Kin (Kin % 4 == 0)
static __device__ __forceinline__ float4 ld4_guard(const float* rowp, int k0, int Kin) {
    bool ok = (k0 + 4 <= Kin);
    const float4* p = reinterpret_cast<const float4*>(rowp + (ok ? k0 : 0));
    float4 v = *p;
    return ok ? v : float4{0.f, 0.f, 0.f, 0.f};
}

static __device__ __forceinline__ bf16x8 ldcvt8(const float* rowp, int k0, int Kin) {
    float4 f0 = ld4_guard(rowp, k0, Kin);
    float4 f1 = ld4_guard(rowp, k0 + 4, Kin);
    bf16x8 r;
    r[0] = f2b(f0.x); r[1] = f2b(f0.y); r[2] = f2b(f0.z); r[3] = f2b(f0.w);
    r[4] = f2b(f1.x); r[5] = f2b(f1.y); r[6] = f2b(f1.z); r[7] = f2b(f1.w);
    return r;
}

// ======================= weight repack: f32 W[K][N] -> bf16 frag layout =======================
__global__ void repack_w_kernel(const float* __restrict__ W, short* __restrict__ out,
                                int K, int N, int KT)
{
    int idx = blockIdx.x * blockDim.x + threadIdx.x;
    int total = (N >> 4) * KT * 512;
    if (idx >= total) return;
    int j    = idx & 7;
    int lane = (idx >> 3) & 63;
    int grp  = idx >> 9;
    int kk   = grp % KT, nt = grp / KT;
    int k    = kk * 32 + (lane >> 4) * 8 + j;
    int col  = nt * 16 + (lane & 15);
    out[idx] = (k < K) ? f2b(W[(size_t)k * N + col]) : (short)0;
}

// ======================= encoder MFMA: f32 in, relu->LN, bf16 table out =======================
template<int NT, int KT>
__global__ __launch_bounds__(256) void enc_mfma_kernel(
    const float* __restrict__ A1, int Kin1,
    const bf16x8* __restrict__ W1,
    const float* __restrict__ bias, const float* __restrict__ g, const float* __restrict__ beta,
    short* __restrict__ outB, int mtiles)
{
    constexpr int N = NT * 16;
    const int lane = threadIdx.x & 63;
    const int wave = threadIdx.x >> 6;
    const int t = blockIdx.x * 4 + wave;
    if (t >= mtiles) return;

    const int lr = lane & 15;
    const int lk = lane >> 4;
    const int row = t * 16 + lr;
    const float* a1p = A1 + (size_t)row * Kin1;

    f32x4 acc[NT];
#pragma unroll
    for (int n = 0; n < NT; ++n) acc[n] = f32x4{0.f, 0.f, 0.f, 0.f};

#pragma unroll
    for (int kk = 0; kk < KT; ++kk) {
        const int k0 = kk * 32 + lk * 8;
        bf16x8 a1 = ldcvt8(a1p, k0, Kin1);
#pragma unroll
        for (int n = 0; n < NT; ++n) {
            bf16x8 b1 = W1[(size_t)(n * KT + kk) * 64 + lane];
            acc[n] = __builtin_amdgcn_mfma_f32_16x16x32_bf16(a1, b1, acc[n], 0, 0, 0);
        }
    }

    const int rowbase = t * 16;
    float v[NT][4];
#pragma unroll
    for (int n = 0; n < NT; ++n) {
        const float bc = bias[n * 16 + lr];
#pragma unroll
        for (int q = 0; q < 4; ++q) v[n][q] = fmaxf(acc[n][q] + bc, 0.f);
    }
    float gcol[NT], becol[NT];
#pragma unroll
    for (int n = 0; n < NT; ++n) { gcol[n] = g[n * 16 + lr]; becol[n] = beta[n * 16 + lr]; }
#pragma unroll
    for (int q = 0; q < 4; ++q) {
        float s = 0.f, ss = 0.f;
#pragma unroll
        for (int n = 0; n < NT; ++n) { s += v[n][q]; ss += v[n][q] * v[n][q]; }
#pragma unroll
        for (int m = 1; m < 16; m <<= 1) {
            s  += __shfl_xor(s, m);
            ss += __shfl_xor(ss, m);
        }
        const float mu   = s * (1.f / N);
        const float rstd = rsqrtf(ss * (1.f / N) - mu * mu + 1e-5f);
#pragma unroll
        for (int n = 0; n < NT; ++n) {
            float o = (v[n][q] - mu) * rstd * gcol[n] + becol[n];
            outB[(size_t)(rowbase + lk * 4 + q) * N + n * 16 + lr] = f2b(o);
        }
    }
}

// ======================= sage1 fused: int-sum gather + dual MFMA + LN->relu, bf16 out =======================
__global__ __launch_bounds__(256) void sage1_fused_kernel(
    const unsigned short* __restrict__ gfeat,
    const int* __restrict__ rowptr, int rowbase, const int* __restrict__ nbr,
    const bf16x8* __restrict__ A2b,
    const bf16x8* __restrict__ W1, const bf16x8* __restrict__ W2,
    const float* __restrict__ bias, const float* __restrict__ g, const float* __restrict__ beta,
    short* __restrict__ out, int mtiles)
{
    constexpr int NT = 8, KT = 4, N = 128;
    const int lane = threadIdx.x & 63;
    const int wave = threadIdx.x >> 6;
    const int t = blockIdx.x * 4 + wave;
    if (t >= mtiles) return;

    const int lr = lane & 15;
    const int lk = lane >> 4;
    const int row = t * 16 + lr;

    const int beg = rowptr[rowbase + row];
    const int end = rowptr[rowbase + row + 1];
    int iacc[KT][8];
#pragma unroll
    for (int kk = 0; kk < KT; ++kk)
#pragma unroll
        for (int j = 0; j < 8; ++j) iacc[kk][j] = 0;

    for (int i = beg; i < end; ++i) {
        const int nb = nbr[i];
        const u16x8* rp = reinterpret_cast<const u16x8*>(gfeat + (size_t)nb * 128);
#pragma unroll
        for (int kk = 0; kk < KT; ++kk) {
            u16x8 vv = rp[kk * 4 + lk];
#pragma unroll
            for (int j = 0; j < 8; ++j) iacc[kk][j] += q16(vv[j]);
        }
    }
    const int cnt = end - beg;
    const float sc = ((cnt > 0) ? (1.f / (float)cnt) : 0.f) * QINV;
    bf16x8 a1f[KT];
#pragma unroll
    for (int kk = 0; kk < KT; ++kk)
#pragma unroll
        for (int j = 0; j < 8; ++j) a1f[kk][j] = f2b((float)iacc[kk][j] * sc);

    f32x4 acc[NT];
#pragma unroll
    for (int n = 0; n < NT; ++n) acc[n] = f32x4{0.f, 0.f, 0.f, 0.f};
#pragma unroll
    for (int kk = 0; kk < KT; ++kk) {
        bf16x8 a2 = A2b[(size_t)row * (KT * 4) + kk * 4 + lk];
#pragma unroll
        for (int n = 0; n < NT; ++n) {
            bf16x8 b1 = W1[(size_t)(n * KT + kk) * 64 + lane];
            acc[n] = __builtin_amdgcn_mfma_f32_16x16x32_bf16(a1f[kk], b1, acc[n], 0, 0, 0);
            bf16x8 b2 = W2[(size_t)(n * KT + kk) * 64 + lane];
            acc[n] = __builtin_amdgcn_mfma_f32_16x16x32_bf16(a2, b2, acc[n], 0, 0, 0);
        }
    }

    const int rowbase2 = t * 16;
    float v[NT][4];
#pragma unroll
    for (int n = 0; n < NT; ++n) {
        const float bc = bias[n * 16 + lr];
#pragma unroll
        for (int q = 0; q < 4; ++q) v[n][q] = acc[n][q] + bc;
    }
    float gcol[NT], becol[NT];
#pragma unroll
    for (int n = 0; n < NT; ++n) { gcol[n] = g[n * 16 + lr]; becol[n] = beta[n * 16 + lr]; }
#pragma unroll
    for (int q = 0; q < 4; ++q) {
        float s = 0.f, ss = 0.f;
#pragma unroll
        for (int n = 0; n < NT; ++n) { s += v[n][q]; ss += v[n][q] * v[n][q]; }
#pragma unroll
        for (int m = 1; m < 16; m <<= 1) {
            s  += __shfl_xor(s, m);
            ss += __shfl_xor(ss, m);
        }
        const float mu   = s * (1.f / N);
        const float rstd = rsqrtf(ss * (1.f / N) - mu * mu + 1e-5f);
#pragma unroll
        for (int n = 0; n < NT; ++n) {
            float o = fmaxf((v[n][q] - mu) * rstd * gcol[n] + becol[n], 0.f);
            out[(size_t)(rowbase2 + lk * 4 + q) * N + n * 16 + lr] = f2b(o);
        }
    }
}

// ======================= CSR build =======================
__global__ void deg_csr_kernel(const int* __restrict__ src, const int* __restrict__ dst,
                               int* __restrict__ deg, int NM, int E)
{
    int e = blockIdx.x * blockDim.x + threadIdx.x;
    if (e < E) {
        atomicAdd(&deg[dst[e]], 1);
        atomicAdd(&deg[NM + src[e]], 1);
    }
}

__global__ void scan_partial_kernel(int* __restrict__ data, int* __restrict__ partials, int N)
{
    __shared__ int sh[256];
    const int tid = threadIdx.x;
    const int base = blockIdx.x * 4096 + tid * 16;
    int vals[16];
    int s = 0;
#pragma unroll
    for (int i = 0; i < 16; ++i) {
        int v = (base + i < N) ? data[base + i] : 0;
        vals[i] = s;
        s += v;
    }
    sh[tid] = s;
    __syncthreads();
    for (int off = 1; off < 256; off <<= 1) {
        int t = 0;
        if (tid >= off) t = sh[tid - off];
        __syncthreads();
        sh[tid] += t;
        __syncthreads();
    }
    int excl = (tid == 0) ? 0 : sh[tid - 1];
    if (tid == 255) partials[blockIdx.x] = sh[255];
#pragma unroll
    for (int i = 0; i < 16; ++i)
        if (base + i < N) data[base + i] = excl + vals[i];
}

__global__ void scan_add_kernel(int* __restrict__ data, const int* __restrict__ partials,
                                int N, int total, int nP)
{
    __shared__ int pref[64];
    const int tid = threadIdx.x;
    if (tid < 64) {
        int v = (tid < nP) ? partials[tid] : 0;
        for (int off = 1; off < 64; off <<= 1) {
            int t = __shfl_up(v, off);
            if (tid >= off) v += t;
        }
        pref[tid] = v;                      // inclusive prefix
    }
    __syncthreads();
    int idx = blockIdx.x * blockDim.x + tid;
    if (idx < N) {
        int p = idx >> 12;
        int excl = (p == 0) ? 0 : pref[p - 1];
        data[idx] += excl;
    }
    if (idx == 0) data[N] = total;
}

// ======================= bucketed fill (write-combining) =======================
__global__ __launch_bounds__(256) void bucket_stage_kernel(
    const int* __restrict__ src, const int* __restrict__ dst,
    const int* __restrict__ rowptr, int* __restrict__ bcur,
    int2* __restrict__ stg, int NM, int NU, int BSZ_M, int BSZ_U, int E)
{
    __shared__ int hist[2 * NB];
    __shared__ int basep[2 * NB];
    __shared__ int bbase[2 * NB];
    const int tid = threadIdx.x;
    const long e0 = (long)blockIdx.x * 2048;

    if (tid < 2 * NB) {
        hist[tid] = 0;
        if (tid < NB) bbase[tid] = rowptr[min(tid * BSZ_M, NM)];
        else          bbase[tid] = rowptr[NM + min((tid - NB) * BSZ_U, NU)];
    }
    __syncthreads();

    int es[8], ed[8];
#pragma unroll
    for (int i = 0; i < 8; ++i) {
        long e = e0 + i * 256 + tid;
        if (e < E) {
            es[i] = src[e]; ed[i] = dst[e];
            atomicAdd(&hist[ed[i] / BSZ_M], 1);
            atomicAdd(&hist[NB + es[i] / BSZ_U], 1);
        } else { es[i] = -1; ed[i] = -1; }
    }
    __syncthreads();
    if (tid < 2 * NB) {
        basep[tid] = atomicAdd(&bcur[tid], hist[tid]);
        hist[tid] = 0;                        // reuse as running in-block cursor
    }
    __syncthreads();
#pragma unroll
    for (int i = 0; i < 8; ++i) {
        if (ed[i] >= 0) {
            int b  = ed[i] / BSZ_M;
            int p  = atomicAdd(&hist[b], 1);
            stg[(long)bbase[b] + basep[b] + p] = make_int2(ed[i], es[i]);
            int b2 = es[i] / BSZ_U;
            int p2 = atomicAdd(&hist[NB + b2], 1);
            stg[(long)bbase[NB + b2] + basep[NB + b2] + p2] = make_int2(NM + es[i], ed[i]);
        }
    }
}

__global__ __launch_bounds__(256) void bucket_commit_kernel(
    const int2* __restrict__ stg, const int* __restrict__ rowptr,
    int* __restrict__ cursor, int* __restrict__ nbr,
    int NM, int NU, int BSZ_M, int BSZ_U)
{
    const int i = blockIdx.x;                 // 0 .. 2*NB-1
    int w0, w1;
    if (i < NB) {
        w0 = rowptr[min(i * BSZ_M, NM)];
        w1 = rowptr[min((i + 1) * BSZ_M, NM)];
    } else {
        int j = i - NB;
        w0 = rowptr[NM + min(j * BSZ_U, NU)];
        w1 = rowptr[NM + min((j + 1) * BSZ_U, NU)];
    }
    for (int k = w0 + (int)threadIdx.x; k < w1; k += (int)blockDim.x) {
        int2 ent = stg[k];
        int slot = rowptr[ent.x] + atomicAdd(&cursor[ent.x], 1);
        nbr[slot] = ent.y;
    }
}

// ======================= projection, dual-output =======================
// outp16     = bf16(feat16 @ wl)            (gathered by the OTHER side)
// outselfp16 = bf16(feat16 @ wr + bl)       (this side's self term for final)
template<int R>
__global__ void proj_kernel(const unsigned short* __restrict__ feat,
                            const float* __restrict__ wl, const float* __restrict__ wr,
                            const float* __restrict__ bl,
                            short* __restrict__ outp, short* __restrict__ outselfp, int n)
{
    __shared__ float4 fs[R][HID / 4];
    const int j = threadIdx.x;               // 0..63
    const int base = blockIdx.x * R;

    for (int t = j; t < R * 16; t += 64) {
        int r = t >> 4, k = t & 15;
        int row = base + r;
        if (row < n) {
            u16x8 v = *(const u16x8*)(feat + (size_t)row * HID + k * 8);
            fs[r][2 * k]     = float4{b2f(v[0]), b2f(v[1]), b2f(v[2]), b2f(v[3])};
            fs[r][2 * k + 1] = float4{b2f(v[4]), b2f(v[5]), b2f(v[6]), b2f(v[7])};
        }
    }
    __syncthreads();

    const float blj = bl[j];
    float accP[R], accS[R];
#pragma unroll
    for (int r = 0; r < R; ++r) { accP[r] = 0.f; accS[r] = blj; }

    for (int k4 = 0; k4 < 32; ++k4) {
        const float* wp = wl + (size_t)(4 * k4) * OUTD + j;
        const float* wq = wr + (size_t)(4 * k4) * OUTD + j;
        float p0 = wp[0 * OUTD], p1 = wp[1 * OUTD], p2 = wp[2 * OUTD], p3 = wp[3 * OUTD];
        float q0 = wq[0 * OUTD], q1 = wq[1 * OUTD], q2 = wq[2 * OUTD], q3 = wq[3 * OUTD];
#pragma unroll
        for (int r = 0; r < R; ++r) {
            float4 v = fs[r][k4];
            accP[r] = fmaf(v.x, p0, accP[r]);
            accP[r] = fmaf(v.y, p1, accP[r]);
            accP[r] = fmaf(v.z, p2, accP[r]);
            accP[r] = fmaf(v.w, p3, accP[r]);
            accS[r] = fmaf(v.x, q0, accS[r]);
            accS[r] = fmaf(v.y, q1, accS[r]);
            accS[r] = fmaf(v.z, q2, accS[r]);
            accS[r] = fmaf(v.w, q3, accS[r]);
        }
    }
    for (int r = 0; r < R; ++r) {
        int row = base + r;
        if (row < n) {
            outp[(size_t)row * OUTD + j]     = f2b(accP[r]);
            outselfp[(size_t)row * OUTD + j] = f2b(accS[r]);
        }
    }
}

// ======================= final fused: 8-way-ILP int-sum gather64 + LN(mean + selfp) =======================
// selfp already holds feat@wr + bl (computed in proj); no LDS, no FMA loop.
template<int R>
__global__ void final_kernel(const unsigned short* __restrict__ pfeat,
                             const int* __restrict__ rowptr, int rowbase,
                             const int* __restrict__ nbr,
                             const unsigned short* __restrict__ selfp,
                             const float* __restrict__ g, const float* __restrict__ beta,
                             float* __restrict__ out, int n)
{
    const int j = threadIdx.x;               // 0..63
    const int base = blockIdx.x * R;

    const float gv = g[j], bv = beta[j];
#pragma unroll
    for (int r = 0; r < R; ++r) {
        int row = base + r;
        float v = 0.f;
        if (row < n) {
            const int beg = rowptr[rowbase + row];
            const int end = rowptr[rowbase + row + 1];
            int s0 = 0, s1 = 0, s2 = 0, s3 = 0, s4 = 0, s5 = 0, s6 = 0, s7 = 0;
            int i = beg;
            for (; i + 7 < end; i += 8) {
                int n0 = nbr[i],     n1 = nbr[i + 1], n2 = nbr[i + 2], n3 = nbr[i + 3];
                int n4 = nbr[i + 4], n5 = nbr[i + 5], n6 = nbr[i + 6], n7 = nbr[i + 7];
                s0 += q16(pfeat[(size_t)n0 * OUTD + j]);
                s1 += q16(pfeat[(size_t)n1 * OUTD + j]);
                s2 += q16(pfeat[(size_t)n2 * OUTD + j]);
                s3 += q16(pfeat[(size_t)n3 * OUTD + j]);
                s4 += q16(pfeat[(size_t)n4 * OUTD + j]);
                s5 += q16(pfeat[(size_t)n5 * OUTD + j]);
                s6 += q16(pfeat[(size_t)n6 * OUTD + j]);
                s7 += q16(pfeat[(size_t)n7 * OUTD + j]);
            }
            for (; i + 3 < end; i += 4) {
                int n0 = nbr[i], n1 = nbr[i + 1], n2 = nbr[i + 2], n3 = nbr[i + 3];
                s0 += q16(pfeat[(size_t)n0 * OUTD + j]);
                s1 += q16(pfeat[(size_t)n1 * OUTD + j]);
                s2 += q16(pfeat[(size_t)n2 * OUTD + j]);
                s3 += q16(pfeat[(size_t)n3 * OUTD + j]);
            }
            for (; i < end; ++i)
                s0 += q16(pfeat[(size_t)nbr[i] * OUTD + j]);
            int isum = ((s0 + s1) + (s2 + s3)) + ((s4 + s5) + (s6 + s7));
            const int cnt = end - beg;
            const float sc = ((cnt > 0) ? (1.f / (float)cnt) : 0.f) * QINV;
            v = (float)isum * sc + b2f(selfp[(size_t)row * OUTD + j]);
        }
        float s = v, q = v * v;
        for (int o = 32; o > 0; o >>= 1) { s += __shfl_down(s, o); q += __shfl_down(q, o); }
        s = __shfl(s, 0); q = __shfl(q, 0);
        float mu = s * (1.f / OUTD);
        float rstd = rsqrtf(q * (1.f / OUTD) - mu * mu + 1e-5f);
        if (row < n) out[(size_t)row * OUTD + j] = (v - mu) * rstd * gv + bv;
    }
}

extern "C" void kernel_launch(void* const* d_in, const int* in_sizes, int n_in,
                              void* d_out, int out_size, void* d_ws, size_t ws_size,
                              hipStream_t stream)
{
    const float* x_user   = (const float*)d_in[0];
    const float* x_movie  = (const float*)d_in[1];
    const int*   src      = (const int*)d_in[2];
    const int*   dst      = (const int*)d_in[3];
    const float* enc_u_w  = (const float*)d_in[4];
    const float* enc_u_b  = (const float*)d_in[5];
    const float* enc_u_g  = (const float*)d_in[6];
    const float* enc_u_be = (const float*)d_in[7];
    const float* enc_m_w  = (const float*)d_in[8];
    const float* enc_m_b  = (const float*)d_in[9];
    const float* enc_m_g  = (const float*)d_in[10];
    const float* enc_m_be = (const float*)d_in[11];
    const float* c1_m_wl  = (const float*)d_in[12];
    const float* c1_m_bl  = (const float*)d_in[13];
    const float* c1_m_wr  = (const float*)d_in[14];
    const float* c1_u_wl  = (const float*)d_in[15];
    const float* c1_u_bl  = (const float*)d_in[16];
    const float* c1_u_wr  = (const float*)d_in[17];
    const float* ln1_u_g  = (const float*)d_in[18];
    const float* ln1_u_b  = (const float*)d_in[19];
    const float* ln1_m_g  = (const float*)d_in[20];
    const float* ln1_m_b  = (const float*)d_in[21];
    const float* c2_m_wl  = (const float*)d_in[22];
    const float* c2_m_bl  = (const float*)d_in[23];
    const float* c2_m_wr  = (const float*)d_in[24];
    const float* c2_u_wl  = (const float*)d_in[25];
    const float* c2_u_bl  = (const float*)d_in[26];
    const float* c2_u_wr  = (const float*)d_in[27];
    const float* ln2_u_g  = (const float*)d_in[28];
    const float* ln2_u_b  = (const float*)d_in[29];
    const float* ln2_m_g  = (const float*)d_in[30];
    const float* ln2_m_b  = (const float*)d_in[31];

    const int NU = in_sizes[0] / 16;
    const int NM = in_sizes[1] / FMDIM;
    const int E  = in_sizes[2];
    const int N  = NM + NU;
    const int BSZ_M = (NM + NB - 1) / NB;
    const int BSZ_U = (NU + NB - 1) / NB;

    // -------- workspace layout (all bf16 tables; no overlays) --------
    short* hub16   = (short*)d_ws;                      // NU*128 bf16 (enc_u out)
    short* hmb16   = hub16 + (size_t)NU * HID;          // NM*128 bf16 (enc_m out)
    short* u1b16   = hmb16 + (size_t)NM * HID;          // NU*128 bf16 (sage1_u out)
    short* m1b16   = u1b16 + (size_t)NU * HID;          // NM*128 bf16 (sage1_m out)
    short* pub16   = m1b16 + (size_t)NM * HID;          // NU*64 bf16 (proj_u gather-out)
    short* pmb16   = pub16 + (size_t)NU * OUTD;         // NM*64 bf16 (proj_m gather-out)
    short* selfpu16= pmb16 + (size_t)NM * OUTD;         // NU*64 bf16 (u1@c2_u_wr + bl)
    short* selfpm16= selfpu16 + (size_t)NU * OUTD;      // NM*64 bf16 (m1@c2_m_wr + bl)
    short* wfu   = selfpm16 + (size_t)NM * OUTD;
    short* wfm   = wfu   + 8 * 1  * 512;
    short* wf1ml = wfm   + 8 * 13 * 512;
    short* wf1mr = wf1ml + 8 * 4  * 512;
    short* wf1ul = wf1mr + 8 * 4  * 512;
    short* wf1ur = wf1ul + 8 * 4  * 512;
    int* rp      = (int*)(wf1ur + 8 * 4 * 512);
    int* cursor  = rp + (N + 1);
    int* partials= cursor + N;
    int* bcur    = partials + 64;                       // 128 bucket cursors
    int* after   = bcur + 128;
    int2* stg    = (int2*)(((uintptr_t)after + 15) & ~(uintptr_t)15);  // 2E staged pairs
    int* nbr     = (int*)(stg + (size_t)2 * E);

    float* out_u = (float*)d_out;
    float* out_m = out_u + (size_t)NU * OUTD;

    // -------- weight repacks (bf16 fragments) --------
    auto repack = [&](const float* W, short* out, int K, int Ncols, int KT) {
        int total = (Ncols >> 4) * KT * 512;
        repack_w_kernel<<<(total + 255) / 256, 256, 0, stream>>>(W, out, K, Ncols, KT);
    };
    repack(enc_u_w, wfu,   16,  128, 1);
    repack(enc_m_w, wfm,   404, 128, 13);
    repack(c1_m_wl, wf1ml, 128, 128, 4);
    repack(c1_m_wr, wf1mr, 128, 128, 4);
    repack(c1_u_wl, wf1ul, 128, 128, 4);
    repack(c1_u_wr, wf1ur, 128, 128, 4);

    // -------- CSR build (bucketed fill) --------
    hipMemsetAsync(rp, 0, (size_t)(2 * N + 1 + 64 + 128) * sizeof(int), stream);
    deg_csr_kernel<<<(E + 255) / 256, 256, 0, stream>>>(src, dst, rp, NM, E);
    {
        int nP = (N + 4095) / 4096;
        scan_partial_kernel<<<nP, 256, 0, stream>>>(rp, partials, N);
        scan_add_kernel<<<(N + 255) / 256, 256, 0, stream>>>(rp, partials, N, 2 * E, nP);
    }
    bucket_stage_kernel<<<(E + 2047) / 2048, 256, 0, stream>>>(
        src, dst, rp, bcur, stg, NM, NU, BSZ_M, BSZ_U, E);
    bucket_commit_kernel<<<2 * NB, 256, 0, stream>>>(
        stg, rp, cursor, nbr, NM, NU, BSZ_M, BSZ_U);

    const int mtU = NU / 16, mtM = NM / 16;      // 6250, 3125 (exact)
    const int gbU = (mtU + 3) / 4, gbM = (mtM + 3) / 4;

    // -------- encoders: MFMA, relu->LN, bf16 table out --------
    enc_mfma_kernel<8, 1><<<gbU, 256, 0, stream>>>(
        x_user, 16, (const bf16x8*)wfu, enc_u_b, enc_u_g, enc_u_be, hub16, mtU);
    enc_mfma_kernel<8, 13><<<gbM, 256, 0, stream>>>(
        x_movie, FMDIM, (const bf16x8*)wfm, enc_m_b, enc_m_g, enc_m_be, hmb16, mtM);

    // -------- layer-1: fused gather + dual MFMA + LN->relu, bf16 out --------
    sage1_fused_kernel<<<gbM, 256, 0, stream>>>(
        (const unsigned short*)hub16, rp, 0, nbr, (const bf16x8*)hmb16,
        (const bf16x8*)wf1ml, (const bf16x8*)wf1mr,
        c1_m_bl, ln1_m_g, ln1_m_b, m1b16, mtM);
    sage1_fused_kernel<<<gbU, 256, 0, stream>>>(
        (const unsigned short*)hmb16, rp, NM, nbr, (const bf16x8*)hub16,
        (const bf16x8*)wf1ul, (const bf16x8*)wf1ur,
        c1_u_bl, ln1_u_g, ln1_u_b, u1b16, mtU);

    // -------- layer-2 projections: dual-output (gather table + self term) --------
    proj_kernel<8><<<(NU + 7) / 8, 64, 0, stream>>>(
        (const unsigned short*)u1b16, c2_m_wl, c2_u_wr, c2_u_bl, pub16, selfpu16, NU);
    proj_kernel<8><<<(NM + 7) / 8, 64, 0, stream>>>(
        (const unsigned short*)m1b16, c2_u_wl, c2_m_wr, c2_m_bl, pmb16, selfpm16, NM);

    // -------- final: gather64 + selfp + LN -> d_out --------
    final_kernel<8><<<(NU + 7) / 8, 64, 0, stream>>>(
        (const unsigned short*)pmb16, rp, NM, nbr, (const unsigned short*)selfpu16,
        ln2_u_g, ln2_u_b, out_u, NU);
    final_kernel<8><<<(NM + 7) / 8, 64, 0, stream>>>(
        (const unsigned short*)pub16, rp, 0, nbr, (const unsigned short*)selfpm16,
        ln2_m_g, ln2_m_b, out_m, NM);
}

// Round 22
// 497.463 us; speedup vs baseline: 1.0772x; 1.0725x over previous
//
#include <hip/hip_runtime.h>
#include <hip/hip_bf16.h>

#define HID 128
#define OUTD 64
#define FMDIM 404
#define NB 64
#define MAXB 2048

using bf16x8 = __attribute__((ext_vector_type(8))) short;   // 8 bf16 in 4 VGPRs
using f32x4  = __attribute__((ext_vector_type(4))) float;
using u16x8  = __attribute__((ext_vector_type(8))) unsigned short;

#define QSCALE 65536.f
#define QINV   (1.f / 65536.f)

static __device__ __forceinline__ short f2b(float f) {
    __hip_bfloat16 h = __float2bfloat16(f);          // RNE
    return *reinterpret_cast<short*>(&h);
}
static __device__ __forceinline__ float b2f(unsigned short u) {
    return __uint_as_float(((unsigned)u) << 16);
}
// fixed-point quantize for order-independent (associative) gather sums
static __device__ __forceinline__ int q16(unsigned short u) {
    return __float2int_rn(b2f(u) * QSCALE);
}

// guarded float4 load: address always in-bounds, value zero when k0+4 > Kin (Kin % 4 == 0)
static __device__ __forceinline__ float4 ld4_guard(const float* rowp, int k0, int Kin) {
    bool ok = (k0 + 4 <= Kin);
    const float4* p = reinterpret_cast<const float4*>(rowp + (ok ? k0 : 0));
    float4 v = *p;
    return ok ? v : float4{0.f, 0.f, 0.f, 0.f};
}

static __device__ __forceinline__ bf16x8 ldcvt8(const float* rowp, int k0, int Kin) {
    float4 f0 = ld4_guard(rowp, k0, Kin);
    float4 f1 = ld4_guard(rowp, k0 + 4, Kin);
    bf16x8 r;
    r[0] = f2b(f0.x); r[1] = f2b(f0.y); r[2] = f2b(f0.z); r[3] = f2b(f0.w);
    r[4] = f2b(f1.x); r[5] = f2b(f1.y); r[6] = f2b(f1.z); r[7] = f2b(f1.w);
    return r;
}

// ======================= weight repack: f32 W[K][N] -> bf16 frag layout =======================
__global__ void repack_w_kernel(const float* __restrict__ W, short* __restrict__ out,
                                int K, int N, int KT)
{
    int idx = blockIdx.x * blockDim.x + threadIdx.x;
    int total = (N >> 4) * KT * 512;
    if (idx >= total) return;
    int j    = idx & 7;
    int lane = (idx >> 3) & 63;
    int grp  = idx >> 9;
    int kk   = grp % KT, nt = grp / KT;
    int k    = kk * 32 + (lane >> 4) * 8 + j;
    int col  = nt * 16 + (lane & 15);
    out[idx] = (k < K) ? f2b(W[(size_t)k * N + col]) : (short)0;
}

// ======================= encoder MFMA: f32 in, relu->LN, bf16 table out =======================
template<int NT, int KT>
__global__ __launch_bounds__(256) void enc_mfma_kernel(
    const float* __restrict__ A1, int Kin1,
    const bf16x8* __restrict__ W1,
    const float* __restrict__ bias, const float* __restrict__ g, const float* __restrict__ beta,
    short* __restrict__ outB, int mtiles)
{
    constexpr int N = NT * 16;
    const int lane = threadIdx.x & 63;
    const int wave = threadIdx.x >> 6;
    const int t = blockIdx.x * 4 + wave;
    if (t >= mtiles) return;

    const int lr = lane & 15;
    const int lk = lane >> 4;
    const int row = t * 16 + lr;
    const float* a1p = A1 + (size_t)row * Kin1;

    f32x4 acc[NT];
#pragma unroll
    for (int n = 0; n < NT; ++n) acc[n] = f32x4{0.f, 0.f, 0.f, 0.f};

#pragma unroll
    for (int kk = 0; kk < KT; ++kk) {
        const int k0 = kk * 32 + lk * 8;
        bf16x8 a1 = ldcvt8(a1p, k0, Kin1);
#pragma unroll
        for (int n = 0; n < NT; ++n) {
            bf16x8 b1 = W1[(size_t)(n * KT + kk) * 64 + lane];
            acc[n] = __builtin_amdgcn_mfma_f32_16x16x32_bf16(a1, b1, acc[n], 0, 0, 0);
        }
    }

    const int rowbase = t * 16;
    float v[NT][4];
#pragma unroll
    for (int n = 0; n < NT; ++n) {
        const float bc = bias[n * 16 + lr];
#pragma unroll
        for (int q = 0; q < 4; ++q) v[n][q] = fmaxf(acc[n][q] + bc, 0.f);
    }
    float gcol[NT], becol[NT];
#pragma unroll
    for (int n = 0; n < NT; ++n) { gcol[n] = g[n * 16 + lr]; becol[n] = beta[n * 16 + lr]; }
#pragma unroll
    for (int q = 0; q < 4; ++q) {
        float s = 0.f, ss = 0.f;
#pragma unroll
        for (int n = 0; n < NT; ++n) { s += v[n][q]; ss += v[n][q] * v[n][q]; }
#pragma unroll
        for (int m = 1; m < 16; m <<= 1) {
            s  += __shfl_xor(s, m);
            ss += __shfl_xor(ss, m);
        }
        const float mu   = s * (1.f / N);
        const float rstd = rsqrtf(ss * (1.f / N) - mu * mu + 1e-5f);
#pragma unroll
        for (int n = 0; n < NT; ++n) {
            float o = (v[n][q] - mu) * rstd * gcol[n] + becol[n];
            outB[(size_t)(rowbase + lk * 4 + q) * N + n * 16 + lr] = f2b(o);
        }
    }
}

// ======================= sage1 fused: int-sum gather + dual MFMA + LN->relu, bf16 out =======================
__global__ __launch_bounds__(256) void sage1_fused_kernel(
    const unsigned short* __restrict__ gfeat,
    const int* __restrict__ rowptr, int rowbase, const int* __restrict__ nbr,
    const bf16x8* __restrict__ A2b,
    const bf16x8* __restrict__ W1, const bf16x8* __restrict__ W2,
    const float* __restrict__ bias, const float* __restrict__ g, const float* __restrict__ beta,
    short* __restrict__ out, int mtiles)
{
    constexpr int NT = 8, KT = 4, N = 128;
    const int lane = threadIdx.x & 63;
    const int wave = threadIdx.x >> 6;
    const int t = blockIdx.x * 4 + wave;
    if (t >= mtiles) return;

    const int lr = lane & 15;
    const int lk = lane >> 4;
    const int row = t * 16 + lr;

    const int beg = rowptr[rowbase + row];
    const int end = rowptr[rowbase + row + 1];
    int iacc[KT][8];
#pragma unroll
    for (int kk = 0; kk < KT; ++kk)
#pragma unroll
        for (int j = 0; j < 8; ++j) iacc[kk][j] = 0;

    for (int i = beg; i < end; ++i) {
        const int nb = nbr[i];
        const u16x8* rp = reinterpret_cast<const u16x8*>(gfeat + (size_t)nb * 128);
#pragma unroll
        for (int kk = 0; kk < KT; ++kk) {
            u16x8 vv = rp[kk * 4 + lk];
#pragma unroll
            for (int j = 0; j < 8; ++j) iacc[kk][j] += q16(vv[j]);
        }
    }
    const int cnt = end - beg;
    const float sc = ((cnt > 0) ? (1.f / (float)cnt) : 0.f) * QINV;
    bf16x8 a1f[KT];
#pragma unroll
    for (int kk = 0; kk < KT; ++kk)
#pragma unroll
        for (int j = 0; j < 8; ++j) a1f[kk][j] = f2b((float)iacc[kk][j] * sc);

    f32x4 acc[NT];
#pragma unroll
    for (int n = 0; n < NT; ++n) acc[n] = f32x4{0.f, 0.f, 0.f, 0.f};
#pragma unroll
    for (int kk = 0; kk < KT; ++kk) {
        bf16x8 a2 = A2b[(size_t)row * (KT * 4) + kk * 4 + lk];
#pragma unroll
        for (int n = 0; n < NT; ++n) {
            bf16x8 b1 = W1[(size_t)(n * KT + kk) * 64 + lane];
            acc[n] = __builtin_amdgcn_mfma_f32_16x16x32_bf16(a1f[kk], b1, acc[n], 0, 0, 0);
            bf16x8 b2 = W2[(size_t)(n * KT + kk) * 64 + lane];
            acc[n] = __builtin_amdgcn_mfma_f32_16x16x32_bf16(a2, b2, acc[n], 0, 0, 0);
        }
    }

    const int rowbase2 = t * 16;
    float v[NT][4];
#pragma unroll
    for (int n = 0; n < NT; ++n) {
        const float bc = bias[n * 16 + lr];
#pragma unroll
        for (int q = 0; q < 4; ++q) v[n][q] = acc[n][q] + bc;
    }
    float gcol[NT], becol[NT];
#pragma unroll
    for (int n = 0; n < NT; ++n) { gcol[n] = g[n * 16 + lr]; becol[n] = beta[n * 16 + lr]; }
#pragma unroll
    for (int q = 0; q < 4; ++q) {
        float s = 0.f, ss = 0.f;
#pragma unroll
        for (int n = 0; n < NT; ++n) { s += v[n][q]; ss += v[n][q] * v[n][q]; }
#pragma unroll
        for (int m = 1; m < 16; m <<= 1) {
            s  += __shfl_xor(s, m);
            ss += __shfl_xor(ss, m);
        }
        const float mu   = s * (1.f / N);
        const float rstd = rsqrtf(ss * (1.f / N) - mu * mu + 1e-5f);
#pragma unroll
        for (int n = 0; n < NT; ++n) {
            float o = fmaxf((v[n][q] - mu) * rstd * gcol[n] + becol[n], 0.f);
            out[(size_t)(rowbase2 + lk * 4 + q) * N + n * 16 + lr] = f2b(o);
        }
    }
}

// ======================= bucketed CSR build =======================
// Pass H: per-block LDS bucket histogram -> 128 global atomics per block.
__global__ __launch_bounds__(256) void bucket_hist_kernel(
    const int* __restrict__ src, const int* __restrict__ dst,
    int* __restrict__ bhist, int BSZ_M, int BSZ_U, int E)
{
    __shared__ int hist[2 * NB];
    const int tid = threadIdx.x;
    const long e0 = (long)blockIdx.x * 2048;
    if (tid < 2 * NB) hist[tid] = 0;
    __syncthreads();
#pragma unroll
    for (int i = 0; i < 8; ++i) {
        long e = e0 + i * 256 + tid;
        if (e < E) {
            atomicAdd(&hist[dst[e] / BSZ_M], 1);
            atomicAdd(&hist[NB + src[e] / BSZ_U], 1);
        }
    }
    __syncthreads();
    if (tid < 2 * NB && hist[tid]) atomicAdd(&bhist[tid], hist[tid]);
}

// scan 128 bucket counts -> exclusive bases bbase[0..128]
__global__ void bucket_scan_kernel(const int* __restrict__ bhist, int* __restrict__ bbase)
{
    if (threadIdx.x == 0 && blockIdx.x == 0) {
        int run = 0;
        for (int i = 0; i < 2 * NB; ++i) { bbase[i] = run; run += bhist[i]; }
        bbase[2 * NB] = run;
    }
}

// Pass A: stage (row,val) pairs into bucket windows (write-combining).
__global__ __launch_bounds__(256) void bucket_stage_kernel(
    const int* __restrict__ src, const int* __restrict__ dst,
    const int* __restrict__ bbase, int* __restrict__ bcur,
    int2* __restrict__ stg, int NM, int BSZ_M, int BSZ_U, int E)
{
    __shared__ int hist[2 * NB];
    __shared__ int basep[2 * NB];
    __shared__ int bb[2 * NB];
    const int tid = threadIdx.x;
    const long e0 = (long)blockIdx.x * 2048;

    if (tid < 2 * NB) { hist[tid] = 0; bb[tid] = bbase[tid]; }
    __syncthreads();

    int es[8], ed[8];
#pragma unroll
    for (int i = 0; i < 8; ++i) {
        long e = e0 + i * 256 + tid;
        if (e < E) {
            es[i] = src[e]; ed[i] = dst[e];
            atomicAdd(&hist[ed[i] / BSZ_M], 1);
            atomicAdd(&hist[NB + es[i] / BSZ_U], 1);
        } else { es[i] = -1; ed[i] = -1; }
    }
    __syncthreads();
    if (tid < 2 * NB) {
        basep[tid] = atomicAdd(&bcur[tid], hist[tid]);
        hist[tid] = 0;                        // reuse as running in-block cursor
    }
    __syncthreads();
#pragma unroll
    for (int i = 0; i < 8; ++i) {
        if (ed[i] >= 0) {
            int b  = ed[i] / BSZ_M;
            int p  = atomicAdd(&hist[b], 1);
            stg[(long)bb[b] + basep[b] + p] = make_int2(ed[i], es[i]);
            int b2 = es[i] / BSZ_U;
            int p2 = atomicAdd(&hist[NB + b2], 1);
            stg[(long)bb[NB + b2] + basep[NB + b2] + p2] = make_int2(NM + es[i], ed[i]);
        }
    }
}

// Pass D: per-bucket degree count via LDS histogram, coalesced write to rp.
__global__ __launch_bounds__(256) void deg_bucket_kernel(
    const int2* __restrict__ stg, const int* __restrict__ bbase,
    int* __restrict__ deg, int NM, int NU, int BSZ_M, int BSZ_U)
{
    __shared__ int lh[MAXB];
    const int i = blockIdx.x;                 // 0 .. 2*NB-1
    int grow, nr;
    if (i < NB) {
        int r0 = i * BSZ_M;
        grow = r0; nr = min(BSZ_M, NM - r0);
    } else {
        int r0 = (i - NB) * BSZ_U;
        grow = NM + r0; nr = min(BSZ_U, NU - r0);
    }
    if (nr < 0) nr = 0;
    for (int k = threadIdx.x; k < nr; k += blockDim.x) lh[k] = 0;
    __syncthreads();
    const int w0 = bbase[i], w1 = bbase[i + 1];
    for (int k = w0 + (int)threadIdx.x; k < w1; k += (int)blockDim.x) {
        int2 ent = stg[k];
        atomicAdd(&lh[ent.x - grow], 1);
    }
    __syncthreads();
    for (int k = threadIdx.x; k < nr; k += blockDim.x) deg[grow + k] = lh[k];
}

__global__ void scan_partial_kernel(int* __restrict__ data, int* __restrict__ partials, int N)
{
    __shared__ int sh[256];
    const int tid = threadIdx.x;
    const int base = blockIdx.x * 4096 + tid * 16;
    int vals[16];
    int s = 0;
#pragma unroll
    for (int i = 0; i < 16; ++i) {
        int v = (base + i < N) ? data[base + i] : 0;
        vals[i] = s;
        s += v;
    }
    sh[tid] = s;
    __syncthreads();
    for (int off = 1; off < 256; off <<= 1) {
        int t = 0;
        if (tid >= off) t = sh[tid - off];
        __syncthreads();
        sh[tid] += t;
        __syncthreads();
    }
    int excl = (tid == 0) ? 0 : sh[tid - 1];
    if (tid == 255) partials[blockIdx.x] = sh[255];
#pragma unroll
    for (int i = 0; i < 16; ++i)
        if (base + i < N) data[base + i] = excl + vals[i];
}

__global__ void scan_add_kernel(int* __restrict__ data, const int* __restrict__ partials,
                                int N, int total, int nP)
{
    __shared__ int pref[64];
    const int tid = threadIdx.x;
    if (tid < 64) {
        int v = (tid < nP) ? partials[tid] : 0;
        for (int off = 1; off < 64; off <<= 1) {
            int t = __shfl_up(v, off);
            if (tid >= off) v += t;
        }
        pref[tid] = v;                      // inclusive prefix
    }
    __syncthreads();
    int idx = blockIdx.x * blockDim.x + tid;
    if (idx < N) {
        int p = idx >> 12;
        int excl = (p == 0) ? 0 : pref[p - 1];
        data[idx] += excl;
    }
    if (idx == 0) data[N] = total;
}

// Pass B: commit staged pairs into nbr (L2-resident window per block).
__global__ __launch_bounds__(256) void bucket_commit_kernel(
    const int2* __restrict__ stg, const int* __restrict__ bbase,
    const int* __restrict__ rowptr, int* __restrict__ cursor, int* __restrict__ nbr)
{
    const int i = blockIdx.x;                 // 0 .. 2*NB-1
    const int w0 = bbase[i], w1 = bbase[i + 1];
    for (int k = w0 + (int)threadIdx.x; k < w1; k += (int)blockDim.x) {
        int2 ent = stg[k];
        int slot = rowptr[ent.x] + atomicAdd(&cursor[ent.x], 1);
        nbr[slot] = ent.y;
    }
}

// ======================= projection, dual-output =======================
template<int R>
__global__ void proj_kernel(const unsigned short* __restrict__ feat,
                            const float* __restrict__ wl, const float* __restrict__ wr,
                            const float* __restrict__ bl,
                            short* __restrict__ outp, short* __restrict__ outselfp, int n)
{
    __shared__ float4 fs[R][HID / 4];
    const int j = threadIdx.x;               // 0..63
    const int base = blockIdx.x * R;

    for (int t = j; t < R * 16; t += 64) {
        int r = t >> 4, k = t & 15;
        int row = base + r;
        if (row < n) {
            u16x8 v = *(const u16x8*)(feat + (size_t)row * HID + k * 8);
            fs[r][2 * k]     = float4{b2f(v[0]), b2f(v[1]), b2f(v[2]), b2f(v[3])};
            fs[r][2 * k + 1] = float4{b2f(v[4]), b2f(v[5]), b2f(v[6]), b2f(v[7])};
        }
    }
    __syncthreads();

    const float blj = bl[j];
    float accP[R], accS[R];
#pragma unroll
    for (int r = 0; r < R; ++r) { accP[r] = 0.f; accS[r] = blj; }

    for (int k4 = 0; k4 < 32; ++k4) {
        const float* wp = wl + (size_t)(4 * k4) * OUTD + j;
        const float* wq = wr + (size_t)(4 * k4) * OUTD + j;
        float p0 = wp[0 * OUTD], p1 = wp[1 * OUTD], p2 = wp[2 * OUTD], p3 = wp[3 * OUTD];
        float q0 = wq[0 * OUTD], q1 = wq[1 * OUTD], q2 = wq[2 * OUTD], q3 = wq[3 * OUTD];
#pragma unroll
        for (int r = 0; r < R; ++r) {
            float4 v = fs[r][k4];
            accP[r] = fmaf(v.x, p0, accP[r]);
            accP[r] = fmaf(v.y, p1, accP[r]);
            accP[r] = fmaf(v.z, p2, accP[r]);
            accP[r] = fmaf(v.w, p3, accP[r]);
            accS[r] = fmaf(v.x, q0, accS[r]);
            accS[r] = fmaf(v.y, q1, accS[r]);
            accS[r] = fmaf(v.z, q2, accS[r]);
            accS[r] = fmaf(v.w, q3, accS[r]);
        }
    }
    for (int r = 0; r < R; ++r) {
        int row = base + r;
        if (row < n) {
            outp[(size_t)row * OUTD + j]     = f2b(accP[r]);
            outselfp[(size_t)row * OUTD + j] = f2b(accS[r]);
        }
    }
}

// ======================= final fused: 8-way-ILP int-sum gather64 + LN(mean + selfp) =======================
template<int R>
__global__ void final_kernel(const unsigned short* __restrict__ pfeat,
                             const int* __restrict__ rowptr, int rowbase,
                             const int* __restrict__ nbr,
                             const unsigned short* __restrict__ selfp,
                             const float* __restrict__ g, const float* __restrict__ beta,
                             float* __restrict__ out, int n)
{
    const int j = threadIdx.x;               // 0..63
    const int base = blockIdx.x * R;

    const float gv = g[j], bv = beta[j];
#pragma unroll
    for (int r = 0; r < R; ++r) {
        int row = base + r;
        float v = 0.f;
        if (row < n) {
            const int beg = rowptr[rowbase + row];
            const int end = rowptr[rowbase + row + 1];
            int s0 = 0, s1 = 0, s2 = 0, s3 = 0, s4 = 0, s5 = 0, s6 = 0, s7 = 0;
            int i = beg;
            for (; i + 7 < end; i += 8) {
                int n0 = nbr[i],     n1 = nbr[i + 1], n2 = nbr[i + 2], n3 = nbr[i + 3];
                int n4 = nbr[i + 4], n5 = nbr[i + 5], n6 = nbr[i + 6], n7 = nbr[i + 7];
                s0 += q16(pfeat[(size_t)n0 * OUTD + j]);
                s1 += q16(pfeat[(size_t)n1 * OUTD + j]);
                s2 += q16(pfeat[(size_t)n2 * OUTD + j]);
                s3 += q16(pfeat[(size_t)n3 * OUTD + j]);
                s4 += q16(pfeat[(size_t)n4 * OUTD + j]);
                s5 += q16(pfeat[(size_t)n5 * OUTD + j]);
                s6 += q16(pfeat[(size_t)n6 * OUTD + j]);
                s7 += q16(pfeat[(size_t)n7 * OUTD + j]);
            }
            for (; i + 3 < end; i += 4) {
                int n0 = nbr[i], n1 = nbr[i + 1], n2 = nbr[i + 2], n3 = nbr[i + 3];
                s0 += q16(pfeat[(size_t)n0 * OUTD + j]);
                s1 += q16(pfeat[(size_t)n1 * OUTD + j]);
                s2 += q16(pfeat[(size_t)n2 * OUTD + j]);
                s3 += q16(pfeat[(size_t)n3 * OUTD + j]);
            }
            for (; i < end; ++i)
                s0 += q16(pfeat[(size_t)nbr[i] * OUTD + j]);
            int isum = ((s0 + s1) + (s2 + s3)) + ((s4 + s5) + (s6 + s7));
            const int cnt = end - beg;
            const float sc = ((cnt > 0) ? (1.f / (float)cnt) : 0.f) * QINV;
            v = (float)isum * sc + b2f(selfp[(size_t)row * OUTD + j]);
        }
        float s = v, q = v * v;
        for (int o = 32; o > 0; o >>= 1) { s += __shfl_down(s, o); q += __shfl_down(q, o); }
        s = __shfl(s, 0); q = __shfl(q, 0);
        float mu = s * (1.f / OUTD);
        float rstd = rsqrtf(q * (1.f / OUTD) - mu * mu + 1e-5f);
        if (row < n) out[(size_t)row * OUTD + j] = (v - mu) * rstd * gv + bv;
    }
}

extern "C" void kernel_launch(void* const* d_in, const int* in_sizes, int n_in,
                              void* d_out, int out_size, void* d_ws, size_t ws_size,
                              hipStream_t stream)
{
    const float* x_user   = (const float*)d_in[0];
    const float* x_movie  = (const float*)d_in[1];
    const int*   src      = (const int*)d_in[2];
    const int*   dst      = (const int*)d_in[3];
    const float* enc_u_w  = (const float*)d_in[4];
    const float* enc_u_b  = (const float*)d_in[5];
    const float* enc_u_g  = (const float*)d_in[6];
    const float* enc_u_be = (const float*)d_in[7];
    const float* enc_m_w  = (const float*)d_in[8];
    const float* enc_m_b  = (const float*)d_in[9];
    const float* enc_m_g  = (const float*)d_in[10];
    const float* enc_m_be = (const float*)d_in[11];
    const float* c1_m_wl  = (const float*)d_in[12];
    const float* c1_m_bl  = (const float*)d_in[13];
    const float* c1_m_wr  = (const float*)d_in[14];
    const float* c1_u_wl  = (const float*)d_in[15];
    const float* c1_u_bl  = (const float*)d_in[16];
    const float* c1_u_wr  = (const float*)d_in[17];
    const float* ln1_u_g  = (const float*)d_in[18];
    const float* ln1_u_b  = (const float*)d_in[19];
    const float* ln1_m_g  = (const float*)d_in[20];
    const float* ln1_m_b  = (const float*)d_in[21];
    const float* c2_m_wl  = (const float*)d_in[22];
    const float* c2_m_bl  = (const float*)d_in[23];
    const float* c2_m_wr  = (const float*)d_in[24];
    const float* c2_u_wl  = (const float*)d_in[25];
    const float* c2_u_bl  = (const float*)d_in[26];
    const float* c2_u_wr  = (const float*)d_in[27];
    const float* ln2_u_g  = (const float*)d_in[28];
    const float* ln2_u_b  = (const float*)d_in[29];
    const float* ln2_m_g  = (const float*)d_in[30];
    const float* ln2_m_b  = (const float*)d_in[31];

    const int NU = in_sizes[0] / 16;
    const int NM = in_sizes[1] / FMDIM;
    const int E  = in_sizes[2];
    const int N  = NM + NU;
    const int BSZ_M = (NM + NB - 1) / NB;
    const int BSZ_U = (NU + NB - 1) / NB;

    // -------- workspace layout (all bf16 tables; no overlays) --------
    short* hub16   = (short*)d_ws;                      // NU*128 bf16 (enc_u out)
    short* hmb16   = hub16 + (size_t)NU * HID;          // NM*128 bf16 (enc_m out)
    short* u1b16   = hmb16 + (size_t)NM * HID;          // NU*128 bf16 (sage1_u out)
    short* m1b16   = u1b16 + (size_t)NU * HID;          // NM*128 bf16 (sage1_m out)
    short* pub16   = m1b16 + (size_t)NM * HID;          // NU*64 bf16 (proj_u gather-out)
    short* pmb16   = pub16 + (size_t)NU * OUTD;         // NM*64 bf16 (proj_m gather-out)
    short* selfpu16= pmb16 + (size_t)NM * OUTD;         // NU*64 bf16 (u1@c2_u_wr + bl)
    short* selfpm16= selfpu16 + (size_t)NU * OUTD;      // NM*64 bf16 (m1@c2_m_wr + bl)
    short* wfu   = selfpm16 + (size_t)NM * OUTD;
    short* wfm   = wfu   + 8 * 1  * 512;
    short* wf1ml = wfm   + 8 * 13 * 512;
    short* wf1mr = wf1ml + 8 * 4  * 512;
    short* wf1ul = wf1mr + 8 * 4  * 512;
    short* wf1ur = wf1ul + 8 * 4  * 512;
    // int region: rp[N+1] | cursor[N] | partials[64] | bhist[128] | bcur[128] | bbase[129] | stg | nbr
    int* rp      = (int*)(wf1ur + 8 * 4 * 512);
    int* cursor  = rp + (N + 1);
    int* partials= cursor + N;
    int* bhist   = partials + 64;
    int* bcur    = bhist + 2 * NB;
    int* bbase   = bcur + 2 * NB;                       // 2*NB+1 entries
    int* after   = bbase + (2 * NB + 1);
    int2* stg    = (int2*)(((uintptr_t)after + 15) & ~(uintptr_t)15);  // 2E staged pairs
    int* nbr     = (int*)(stg + (size_t)2 * E);

    float* out_u = (float*)d_out;
    float* out_m = out_u + (size_t)NU * OUTD;

    // -------- weight repacks (bf16 fragments) --------
    auto repack = [&](const float* W, short* out, int K, int Ncols, int KT) {
        int total = (Ncols >> 4) * KT * 512;
        repack_w_kernel<<<(total + 255) / 256, 256, 0, stream>>>(W, out, K, Ncols, KT);
    };
    repack(enc_u_w, wfu,   16,  128, 1);
    repack(enc_m_w, wfm,   404, 128, 13);
    repack(c1_m_wl, wf1ml, 128, 128, 4);
    repack(c1_m_wr, wf1mr, 128, 128, 4);
    repack(c1_u_wl, wf1ul, 128, 128, 4);
    repack(c1_u_wr, wf1ur, 128, 128, 4);

    // -------- CSR build (fully bucketed: no row-granular global atomics for counting) --------
    // zero rp+cursor+partials+bhist+bcur (contiguous)
    hipMemsetAsync(rp, 0, (size_t)(2 * N + 1 + 64 + 4 * NB) * sizeof(int), stream);
    bucket_hist_kernel<<<(E + 2047) / 2048, 256, 0, stream>>>(src, dst, bhist, BSZ_M, BSZ_U, E);
    bucket_scan_kernel<<<1, 64, 0, stream>>>(bhist, bbase);
    bucket_stage_kernel<<<(E + 2047) / 2048, 256, 0, stream>>>(
        src, dst, bbase, bcur, stg, NM, BSZ_M, BSZ_U, E);
    deg_bucket_kernel<<<2 * NB, 256, 0, stream>>>(stg, bbase, rp, NM, NU, BSZ_M, BSZ_U);
    {
        int nP = (N + 4095) / 4096;
        scan_partial_kernel<<<nP, 256, 0, stream>>>(rp, partials, N);
        scan_add_kernel<<<(N + 255) / 256, 256, 0, stream>>>(rp, partials, N, 2 * E, nP);
    }
    bucket_commit_kernel<<<2 * NB, 256, 0, stream>>>(stg, bbase, rp, cursor, nbr);

    const int mtU = NU / 16, mtM = NM / 16;      // 6250, 3125 (exact)
    const int gbU = (mtU + 3) / 4, gbM = (mtM + 3) / 4;

    // -------- encoders: MFMA, relu->LN, bf16 table out --------
    enc_mfma_kernel<8, 1><<<gbU, 256, 0, stream>>>(
        x_user, 16, (const bf16x8*)wfu, enc_u_b, enc_u_g, enc_u_be, hub16, mtU);
    enc_mfma_kernel<8, 13><<<gbM, 256, 0, stream>>>(
        x_movie, FMDIM, (const bf16x8*)wfm, enc_m_b, enc_m_g, enc_m_be, hmb16, mtM);

    // -------- layer-1: fused gather + dual MFMA + LN->relu, bf16 out --------
    sage1_fused_kernel<<<gbM, 256, 0, stream>>>(
        (const unsigned short*)hub16, rp, 0, nbr, (const bf16x8*)hmb16,
        (const bf16x8*)wf1ml, (const bf16x8*)wf1mr,
        c1_m_bl, ln1_m_g, ln1_m_b, m1b16, mtM);
    sage1_fused_kernel<<<gbU, 256, 0, stream>>>(
        (const unsigned short*)hmb16, rp, NM, nbr, (const bf16x8*)hub16,
        (const bf16x8*)wf1ul, (const bf16x8*)wf1ur,
        c1_u_bl, ln1_u_g, ln1_u_b, u1b16, mtU);

    // -------- layer-2 projections: dual-output (gather table + self term) --------
    proj_kernel<8><<<(NU + 7) / 8, 64, 0, stream>>>(
        (const unsigned short*)u1b16, c2_m_wl, c2_u_wr, c2_u_bl, pub16, selfpu16, NU);
    proj_kernel<8><<<(NM + 7) / 8, 64, 0, stream>>>(
        (const unsigned short*)m1b16, c2_u_wl, c2_m_wr, c2_m_bl, pmb16, selfpm16, NM);

    // -------- final: gather64 + selfp + LN -> d_out --------
    final_kernel<8><<<(NU + 7) / 8, 64, 0, stream>>>(
        (const unsigned short*)pmb16, rp, NM, nbr, (const unsigned short*)selfpu16,
        ln2_u_g, ln2_u_b, out_u, NU);
    final_kernel<8><<<(NM + 7) / 8, 64, 0, stream>>>(
        (const unsigned short*)pub16, rp, 0, nbr, (const unsigned short*)selfpm16,
        ln2_m_g, ln2_m_b, out_m, NM);
}

// Round 23
// 479.860 us; speedup vs baseline: 1.1167x; 1.0367x over previous
//
#include <hip/hip_runtime.h>
#include <hip/hip_bf16.h>

#define HID 128
#define OUTD 64
#define FMDIM 404
#define NB 64
#define MAXB 2048

using bf16x8 = __attribute__((ext_vector_type(8))) short;   // 8 bf16 in 4 VGPRs
using f32x4  = __attribute__((ext_vector_type(4))) float;
using u16x8  = __attribute__((ext_vector_type(8))) unsigned short;

#define QSCALE 65536.f
#define QINV   (1.f / 65536.f)

static __device__ __forceinline__ short f2b(float f) {
    __hip_bfloat16 h = __float2bfloat16(f);          // RNE
    return *reinterpret_cast<short*>(&h);
}
static __device__ __forceinline__ float b2f(unsigned short u) {
    return __uint_as_float(((unsigned)u) << 16);
}
// fixed-point quantize for order-independent (associative) gather sums
static __device__ __forceinline__ int q16(unsigned short u) {
    return __float2int_rn(b2f(u) * QSCALE);
}

// guarded float4 load: address always in-bounds, value zero when k0+4 > Kin (Kin % 4 == 0)
static __device__ __forceinline__ float4 ld4_guard(const float* rowp, int k0, int Kin) {
    bool ok = (k0 + 4 <= Kin);
    const float4* p = reinterpret_cast<const float4*>(rowp + (ok ? k0 : 0));
    float4 v = *p;
    return ok ? v : float4{0.f, 0.f, 0.f, 0.f};
}

static __device__ __forceinline__ bf16x8 ldcvt8(const float* rowp, int k0, int Kin) {
    float4 f0 = ld4_guard(rowp, k0, Kin);
    float4 f1 = ld4_guard(rowp, k0 + 4, Kin);
    bf16x8 r;
    r[0] = f2b(f0.x); r[1] = f2b(f0.y); r[2] = f2b(f0.z); r[3] = f2b(f0.w);
    r[4] = f2b(f1.x); r[5] = f2b(f1.y); r[6] = f2b(f1.z); r[7] = f2b(f1.w);
    return r;
}

// ======================= weight repack: f32 W[K][N] -> bf16 frag layout =======================
__global__ void repack_w_kernel(const float* __restrict__ W, short* __restrict__ out,
                                int K, int N, int KT)
{
    int idx = blockIdx.x * blockDim.x + threadIdx.x;
    int total = (N >> 4) * KT * 512;
    if (idx >= total) return;
    int j    = idx & 7;
    int lane = (idx >> 3) & 63;
    int grp  = idx >> 9;
    int kk   = grp % KT, nt = grp / KT;
    int k    = kk * 32 + (lane >> 4) * 8 + j;
    int col  = nt * 16 + (lane & 15);
    out[idx] = (k < K) ? f2b(W[(size_t)k * N + col]) : (short)0;
}

// ======================= encoder MFMA: f32 in, relu->LN, bf16 table out =======================
template<int NT, int KT>
__global__ __launch_bounds__(256) void enc_mfma_kernel(
    const float* __restrict__ A1, int Kin1,
    const bf16x8* __restrict__ W1,
    const float* __restrict__ bias, const float* __restrict__ g, const float* __restrict__ beta,
    short* __restrict__ outB, int mtiles)
{
    constexpr int N = NT * 16;
    const int lane = threadIdx.x & 63;
    const int wave = threadIdx.x >> 6;
    const int t = blockIdx.x * 4 + wave;
    if (t >= mtiles) return;

    const int lr = lane & 15;
    const int lk = lane >> 4;
    const int row = t * 16 + lr;
    const float* a1p = A1 + (size_t)row * Kin1;

    f32x4 acc[NT];
#pragma unroll
    for (int n = 0; n < NT; ++n) acc[n] = f32x4{0.f, 0.f, 0.f, 0.f};

#pragma unroll
    for (int kk = 0; kk < KT; ++kk) {
        const int k0 = kk * 32 + lk * 8;
        bf16x8 a1 = ldcvt8(a1p, k0, Kin1);
#pragma unroll
        for (int n = 0; n < NT; ++n) {
            bf16x8 b1 = W1[(size_t)(n * KT + kk) * 64 + lane];
            acc[n] = __builtin_amdgcn_mfma_f32_16x16x32_bf16(a1, b1, acc[n], 0, 0, 0);
        }
    }

    const int rowbase = t * 16;
    float v[NT][4];
#pragma unroll
    for (int n = 0; n < NT; ++n) {
        const float bc = bias[n * 16 + lr];
#pragma unroll
        for (int q = 0; q < 4; ++q) v[n][q] = fmaxf(acc[n][q] + bc, 0.f);
    }
    float gcol[NT], becol[NT];
#pragma unroll
    for (int n = 0; n < NT; ++n) { gcol[n] = g[n * 16 + lr]; becol[n] = beta[n * 16 + lr]; }
#pragma unroll
    for (int q = 0; q < 4; ++q) {
        float s = 0.f, ss = 0.f;
#pragma unroll
        for (int n = 0; n < NT; ++n) { s += v[n][q]; ss += v[n][q] * v[n][q]; }
#pragma unroll
        for (int m = 1; m < 16; m <<= 1) {
            s  += __shfl_xor(s, m);
            ss += __shfl_xor(ss, m);
        }
        const float mu   = s * (1.f / N);
        const float rstd = rsqrtf(ss * (1.f / N) - mu * mu + 1e-5f);
#pragma unroll
        for (int n = 0; n < NT; ++n) {
            float o = (v[n][q] - mu) * rstd * gcol[n] + becol[n];
            outB[(size_t)(rowbase + lk * 4 + q) * N + n * 16 + lr] = f2b(o);
        }
    }
}

// ======================= sage1 fused (dual-side launch) =======================
struct S1Args {
    const unsigned short* gfeat;
    const int* rowptr; int rowbase; const int* nbr;
    const bf16x8* A2b;
    const bf16x8* W1; const bf16x8* W2;
    const float* bias; const float* g; const float* beta;
    short* out; int mtiles;
};

static __device__ __forceinline__ void sage1_body(const S1Args& A, int t)
{
    constexpr int NT = 8, KT = 4, N = 128;
    const int lane = threadIdx.x & 63;
    const int lr = lane & 15;
    const int lk = lane >> 4;
    const int row = t * 16 + lr;

    const int beg = A.rowptr[A.rowbase + row];
    const int end = A.rowptr[A.rowbase + row + 1];
    int iacc[KT][8];
#pragma unroll
    for (int kk = 0; kk < KT; ++kk)
#pragma unroll
        for (int j = 0; j < 8; ++j) iacc[kk][j] = 0;

    for (int i = beg; i < end; ++i) {
        const int nb = A.nbr[i];
        const u16x8* rp = reinterpret_cast<const u16x8*>(A.gfeat + (size_t)nb * 128);
#pragma unroll
        for (int kk = 0; kk < KT; ++kk) {
            u16x8 vv = rp[kk * 4 + lk];
#pragma unroll
            for (int j = 0; j < 8; ++j) iacc[kk][j] += q16(vv[j]);
        }
    }
    const int cnt = end - beg;
    const float sc = ((cnt > 0) ? (1.f / (float)cnt) : 0.f) * QINV;
    bf16x8 a1f[KT];
#pragma unroll
    for (int kk = 0; kk < KT; ++kk)
#pragma unroll
        for (int j = 0; j < 8; ++j) a1f[kk][j] = f2b((float)iacc[kk][j] * sc);

    f32x4 acc[NT];
#pragma unroll
    for (int n = 0; n < NT; ++n) acc[n] = f32x4{0.f, 0.f, 0.f, 0.f};
#pragma unroll
    for (int kk = 0; kk < KT; ++kk) {
        bf16x8 a2 = A.A2b[(size_t)row * (KT * 4) + kk * 4 + lk];
#pragma unroll
        for (int n = 0; n < NT; ++n) {
            bf16x8 b1 = A.W1[(size_t)(n * KT + kk) * 64 + lane];
            acc[n] = __builtin_amdgcn_mfma_f32_16x16x32_bf16(a1f[kk], b1, acc[n], 0, 0, 0);
            bf16x8 b2 = A.W2[(size_t)(n * KT + kk) * 64 + lane];
            acc[n] = __builtin_amdgcn_mfma_f32_16x16x32_bf16(a2, b2, acc[n], 0, 0, 0);
        }
    }

    const int rowbase2 = t * 16;
    float v[NT][4];
#pragma unroll
    for (int n = 0; n < NT; ++n) {
        const float bc = A.bias[n * 16 + lr];
#pragma unroll
        for (int q = 0; q < 4; ++q) v[n][q] = acc[n][q] + bc;
    }
    float gcol[NT], becol[NT];
#pragma unroll
    for (int n = 0; n < NT; ++n) { gcol[n] = A.g[n * 16 + lr]; becol[n] = A.beta[n * 16 + lr]; }
#pragma unroll
    for (int q = 0; q < 4; ++q) {
        float s = 0.f, ss = 0.f;
#pragma unroll
        for (int n = 0; n < NT; ++n) { s += v[n][q]; ss += v[n][q] * v[n][q]; }
#pragma unroll
        for (int m = 1; m < 16; m <<= 1) {
            s  += __shfl_xor(s, m);
            ss += __shfl_xor(ss, m);
        }
        const float mu   = s * (1.f / N);
        const float rstd = rsqrtf(ss * (1.f / N) - mu * mu + 1e-5f);
#pragma unroll
        for (int n = 0; n < NT; ++n) {
            float o = fmaxf((v[n][q] - mu) * rstd * gcol[n] + becol[n], 0.f);
            A.out[(size_t)(rowbase2 + lk * 4 + q) * N + n * 16 + lr] = f2b(o);
        }
    }
}

__global__ __launch_bounds__(256) void sage1_dual_kernel(S1Args a, S1Args b, int gbA)
{
    const int blk = blockIdx.x;
    const bool isA = (blk < gbA);
    const S1Args& A = isA ? a : b;
    const int t = (isA ? blk : blk - gbA) * 4 + (int)(threadIdx.x >> 6);
    if (t >= A.mtiles) return;
    sage1_body(A, t);
}

// ======================= bucketed CSR build =======================
__global__ __launch_bounds__(256) void bucket_hist_kernel(
    const int* __restrict__ src, const int* __restrict__ dst,
    int* __restrict__ bhist, int BSZ_M, int BSZ_U, int E)
{
    __shared__ int hist[2 * NB];
    const int tid = threadIdx.x;
    const long e0 = (long)blockIdx.x * 2048;
    if (tid < 2 * NB) hist[tid] = 0;
    __syncthreads();
#pragma unroll
    for (int i = 0; i < 8; ++i) {
        long e = e0 + i * 256 + tid;
        if (e < E) {
            atomicAdd(&hist[dst[e] / BSZ_M], 1);
            atomicAdd(&hist[NB + src[e] / BSZ_U], 1);
        }
    }
    __syncthreads();
    if (tid < 2 * NB && hist[tid]) atomicAdd(&bhist[tid], hist[tid]);
}

__global__ void bucket_scan_kernel(const int* __restrict__ bhist, int* __restrict__ bbase)
{
    if (threadIdx.x == 0 && blockIdx.x == 0) {
        int run = 0;
        for (int i = 0; i < 2 * NB; ++i) { bbase[i] = run; run += bhist[i]; }
        bbase[2 * NB] = run;
    }
}

__global__ __launch_bounds__(256) void bucket_stage_kernel(
    const int* __restrict__ src, const int* __restrict__ dst,
    const int* __restrict__ bbase, int* __restrict__ bcur,
    int2* __restrict__ stg, int NM, int BSZ_M, int BSZ_U, int E)
{
    __shared__ int hist[2 * NB];
    __shared__ int basep[2 * NB];
    __shared__ int bb[2 * NB];
    const int tid = threadIdx.x;
    const long e0 = (long)blockIdx.x * 2048;

    if (tid < 2 * NB) { hist[tid] = 0; bb[tid] = bbase[tid]; }
    __syncthreads();

    int es[8], ed[8];
#pragma unroll
    for (int i = 0; i < 8; ++i) {
        long e = e0 + i * 256 + tid;
        if (e < E) {
            es[i] = src[e]; ed[i] = dst[e];
            atomicAdd(&hist[ed[i] / BSZ_M], 1);
            atomicAdd(&hist[NB + es[i] / BSZ_U], 1);
        } else { es[i] = -1; ed[i] = -1; }
    }
    __syncthreads();
    if (tid < 2 * NB) {
        basep[tid] = atomicAdd(&bcur[tid], hist[tid]);
        hist[tid] = 0;                        // reuse as running in-block cursor
    }
    __syncthreads();
#pragma unroll
    for (int i = 0; i < 8; ++i) {
        if (ed[i] >= 0) {
            int b  = ed[i] / BSZ_M;
            int p  = atomicAdd(&hist[b], 1);
            stg[(long)bb[b] + basep[b] + p] = make_int2(ed[i], es[i]);
            int b2 = es[i] / BSZ_U;
            int p2 = atomicAdd(&hist[NB + b2], 1);
            stg[(long)bb[NB + b2] + basep[NB + b2] + p2] = make_int2(NM + es[i], ed[i]);
        }
    }
}

__global__ __launch_bounds__(256) void deg_bucket_kernel(
    const int2* __restrict__ stg, const int* __restrict__ bbase,
    int* __restrict__ deg, int NM, int NU, int BSZ_M, int BSZ_U)
{
    __shared__ int lh[MAXB];
    const int i = blockIdx.x;                 // 0 .. 2*NB-1
    int grow, nr;
    if (i < NB) {
        int r0 = i * BSZ_M;
        grow = r0; nr = min(BSZ_M, NM - r0);
    } else {
        int r0 = (i - NB) * BSZ_U;
        grow = NM + r0; nr = min(BSZ_U, NU - r0);
    }
    if (nr < 0) nr = 0;
    for (int k = threadIdx.x; k < nr; k += blockDim.x) lh[k] = 0;
    __syncthreads();
    const int w0 = bbase[i], w1 = bbase[i + 1];
    for (int k = w0 + (int)threadIdx.x; k < w1; k += (int)blockDim.x) {
        int2 ent = stg[k];
        atomicAdd(&lh[ent.x - grow], 1);
    }
    __syncthreads();
    for (int k = threadIdx.x; k < nr; k += blockDim.x) deg[grow + k] = lh[k];
}

__global__ void scan_partial_kernel(int* __restrict__ data, int* __restrict__ partials, int N)
{
    __shared__ int sh[256];
    const int tid = threadIdx.x;
    const int base = blockIdx.x * 4096 + tid * 16;
    int vals[16];
    int s = 0;
#pragma unroll
    for (int i = 0; i < 16; ++i) {
        int v = (base + i < N) ? data[base + i] : 0;
        vals[i] = s;
        s += v;
    }
    sh[tid] = s;
    __syncthreads();
    for (int off = 1; off < 256; off <<= 1) {
        int t = 0;
        if (tid >= off) t = sh[tid - off];
        __syncthreads();
        sh[tid] += t;
        __syncthreads();
    }
    int excl = (tid == 0) ? 0 : sh[tid - 1];
    if (tid == 255) partials[blockIdx.x] = sh[255];
#pragma unroll
    for (int i = 0; i < 16; ++i)
        if (base + i < N) data[base + i] = excl + vals[i];
}

__global__ void scan_add_kernel(int* __restrict__ data, const int* __restrict__ partials,
                                int N, int total, int nP)
{
    __shared__ int pref[64];
    const int tid = threadIdx.x;
    if (tid < 64) {
        int v = (tid < nP) ? partials[tid] : 0;
        for (int off = 1; off < 64; off <<= 1) {
            int t = __shfl_up(v, off);
            if (tid >= off) v += t;
        }
        pref[tid] = v;                      // inclusive prefix
    }
    __syncthreads();
    int idx = blockIdx.x * blockDim.x + tid;
    if (idx < N) {
        int p = idx >> 12;
        int excl = (p == 0) ? 0 : pref[p - 1];
        data[idx] += excl;
    }
    if (idx == 0) data[N] = total;
}

__global__ __launch_bounds__(256) void bucket_commit_kernel(
    const int2* __restrict__ stg, const int* __restrict__ bbase,
    const int* __restrict__ rowptr, int* __restrict__ cursor, int* __restrict__ nbr)
{
    const int i = blockIdx.x;                 // 0 .. 2*NB-1
    const int w0 = bbase[i], w1 = bbase[i + 1];
    for (int k = w0 + (int)threadIdx.x; k < w1; k += (int)blockDim.x) {
        int2 ent = stg[k];
        int slot = rowptr[ent.x] + atomicAdd(&cursor[ent.x], 1);
        nbr[slot] = ent.y;
    }
}

// ======================= projection, dual-output, dual-side launch =======================
struct PrArgs {
    const unsigned short* feat;
    const float* wl; const float* wr; const float* bl;
    short* outp; short* outselfp; int n;
};

static __device__ __forceinline__ void proj_body(const PrArgs& A, int blk)
{
    constexpr int R = 8;
    __shared__ float4 fs[R][HID / 4];
    const int j = threadIdx.x;               // 0..63
    const int base = blk * R;

    for (int t = j; t < R * 16; t += 64) {
        int r = t >> 4, k = t & 15;
        int row = base + r;
        if (row < A.n) {
            u16x8 v = *(const u16x8*)(A.feat + (size_t)row * HID + k * 8);
            fs[r][2 * k]     = float4{b2f(v[0]), b2f(v[1]), b2f(v[2]), b2f(v[3])};
            fs[r][2 * k + 1] = float4{b2f(v[4]), b2f(v[5]), b2f(v[6]), b2f(v[7])};
        }
    }
    __syncthreads();

    const float blj = A.bl[j];
    float accP[R], accS[R];
#pragma unroll
    for (int r = 0; r < R; ++r) { accP[r] = 0.f; accS[r] = blj; }

    for (int k4 = 0; k4 < 32; ++k4) {
        const float* wp = A.wl + (size_t)(4 * k4) * OUTD + j;
        const float* wq = A.wr + (size_t)(4 * k4) * OUTD + j;
        float p0 = wp[0 * OUTD], p1 = wp[1 * OUTD], p2 = wp[2 * OUTD], p3 = wp[3 * OUTD];
        float q0 = wq[0 * OUTD], q1 = wq[1 * OUTD], q2 = wq[2 * OUTD], q3 = wq[3 * OUTD];
#pragma unroll
        for (int r = 0; r < R; ++r) {
            float4 v = fs[r][k4];
            accP[r] = fmaf(v.x, p0, accP[r]);
            accP[r] = fmaf(v.y, p1, accP[r]);
            accP[r] = fmaf(v.z, p2, accP[r]);
            accP[r] = fmaf(v.w, p3, accP[r]);
            accS[r] = fmaf(v.x, q0, accS[r]);
            accS[r] = fmaf(v.y, q1, accS[r]);
            accS[r] = fmaf(v.z, q2, accS[r]);
            accS[r] = fmaf(v.w, q3, accS[r]);
        }
    }
    for (int r = 0; r < R; ++r) {
        int row = base + r;
        if (row < A.n) {
            A.outp[(size_t)row * OUTD + j]     = f2b(accP[r]);
            A.outselfp[(size_t)row * OUTD + j] = f2b(accS[r]);
        }
    }
}

__global__ __launch_bounds__(64) void proj_dual_kernel(PrArgs a, PrArgs b, int gbA)
{
    const int blk = blockIdx.x;
    if (blk < gbA) proj_body(a, blk);
    else           proj_body(b, blk - gbA);
}

// ======================= final fused, dual-side launch =======================
struct FnArgs {
    const unsigned short* pfeat;
    const int* rowptr; int rowbase; const int* nbr;
    const unsigned short* selfp;
    const float* g; const float* beta;
    float* out; int n;
};

static __device__ __forceinline__ void final_body(const FnArgs& A, int blk)
{
    constexpr int R = 8;
    const int j = threadIdx.x;               // 0..63
    const int base = blk * R;

    const float gv = A.g[j], bv = A.beta[j];
#pragma unroll
    for (int r = 0; r < R; ++r) {
        int row = base + r;
        float v = 0.f;
        if (row < A.n) {
            const int beg = A.rowptr[A.rowbase + row];
            const int end = A.rowptr[A.rowbase + row + 1];
            int s0 = 0, s1 = 0, s2 = 0, s3 = 0, s4 = 0, s5 = 0, s6 = 0, s7 = 0;
            int i = beg;
            for (; i + 7 < end; i += 8) {
                int n0 = A.nbr[i],     n1 = A.nbr[i + 1], n2 = A.nbr[i + 2], n3 = A.nbr[i + 3];
                int n4 = A.nbr[i + 4], n5 = A.nbr[i + 5], n6 = A.nbr[i + 6], n7 = A.nbr[i + 7];
                s0 += q16(A.pfeat[(size_t)n0 * OUTD + j]);
                s1 += q16(A.pfeat[(size_t)n1 * OUTD + j]);
                s2 += q16(A.pfeat[(size_t)n2 * OUTD + j]);
                s3 += q16(A.pfeat[(size_t)n3 * OUTD + j]);
                s4 += q16(A.pfeat[(size_t)n4 * OUTD + j]);
                s5 += q16(A.pfeat[(size_t)n5 * OUTD + j]);
                s6 += q16(A.pfeat[(size_t)n6 * OUTD + j]);
                s7 += q16(A.pfeat[(size_t)n7 * OUTD + j]);
            }
            for (; i + 3 < end; i += 4) {
                int n0 = A.nbr[i], n1 = A.nbr[i + 1], n2 = A.nbr[i + 2], n3 = A.nbr[i + 3];
                s0 += q16(A.pfeat[(size_t)n0 * OUTD + j]);
                s1 += q16(A.pfeat[(size_t)n1 * OUTD + j]);
                s2 += q16(A.pfeat[(size_t)n2 * OUTD + j]);
                s3 += q16(A.pfeat[(size_t)n3 * OUTD + j]);
            }
            for (; i < end; ++i)
                s0 += q16(A.pfeat[(size_t)A.nbr[i] * OUTD + j]);
            int isum = ((s0 + s1) + (s2 + s3)) + ((s4 + s5) + (s6 + s7));
            const int cnt = end - beg;
            const float sc = ((cnt > 0) ? (1.f / (float)cnt) : 0.f) * QINV;
            v = (float)isum * sc + b2f(A.selfp[(size_t)row * OUTD + j]);
        }
        float s = v, q = v * v;
        for (int o = 32; o > 0; o >>= 1) { s += __shfl_down(s, o); q += __shfl_down(q, o); }
        s = __shfl(s, 0); q = __shfl(q, 0);
        float mu = s * (1.f / OUTD);
        float rstd = rsqrtf(q * (1.f / OUTD) - mu * mu + 1e-5f);
        if (row < A.n) A.out[(size_t)row * OUTD + j] = (v - mu) * rstd * gv + bv;
    }
}

__global__ __launch_bounds__(64) void final_dual_kernel(FnArgs a, FnArgs b, int gbA)
{
    const int blk = blockIdx.x;
    if (blk < gbA) final_body(a, blk);
    else           final_body(b, blk - gbA);
}

extern "C" void kernel_launch(void* const* d_in, const int* in_sizes, int n_in,
                              void* d_out, int out_size, void* d_ws, size_t ws_size,
                              hipStream_t stream)
{
    const float* x_user   = (const float*)d_in[0];
    const float* x_movie  = (const float*)d_in[1];
    const int*   src      = (const int*)d_in[2];
    const int*   dst      = (const int*)d_in[3];
    const float* enc_u_w  = (const float*)d_in[4];
    const float* enc_u_b  = (const float*)d_in[5];
    const float* enc_u_g  = (const float*)d_in[6];
    const float* enc_u_be = (const float*)d_in[7];
    const float* enc_m_w  = (const float*)d_in[8];
    const float* enc_m_b  = (const float*)d_in[9];
    const float* enc_m_g  = (const float*)d_in[10];
    const float* enc_m_be = (const float*)d_in[11];
    const float* c1_m_wl  = (const float*)d_in[12];
    const float* c1_m_bl  = (const float*)d_in[13];
    const float* c1_m_wr  = (const float*)d_in[14];
    const float* c1_u_wl  = (const float*)d_in[15];
    const float* c1_u_bl  = (const float*)d_in[16];
    const float* c1_u_wr  = (const float*)d_in[17];
    const float* ln1_u_g  = (const float*)d_in[18];
    const float* ln1_u_b  = (const float*)d_in[19];
    const float* ln1_m_g  = (const float*)d_in[20];
    const float* ln1_m_b  = (const float*)d_in[21];
    const float* c2_m_wl  = (const float*)d_in[22];
    const float* c2_m_bl  = (const float*)d_in[23];
    const float* c2_m_wr  = (const float*)d_in[24];
    const float* c2_u_wl  = (const float*)d_in[25];
    const float* c2_u_bl  = (const float*)d_in[26];
    const float* c2_u_wr  = (const float*)d_in[27];
    const float* ln2_u_g  = (const float*)d_in[28];
    const float* ln2_u_b  = (const float*)d_in[29];
    const float* ln2_m_g  = (const float*)d_in[30];
    const float* ln2_m_b  = (const float*)d_in[31];

    const int NU = in_sizes[0] / 16;
    const int NM = in_sizes[1] / FMDIM;
    const int E  = in_sizes[2];
    const int N  = NM + NU;
    const int BSZ_M = (NM + NB - 1) / NB;
    const int BSZ_U = (NU + NB - 1) / NB;

    // -------- workspace layout (all bf16 tables; no overlays) --------
    short* hub16   = (short*)d_ws;                      // NU*128 bf16 (enc_u out)
    short* hmb16   = hub16 + (size_t)NU * HID;          // NM*128 bf16 (enc_m out)
    short* u1b16   = hmb16 + (size_t)NM * HID;          // NU*128 bf16 (sage1_u out)
    short* m1b16   = u1b16 + (size_t)NU * HID;          // NM*128 bf16 (sage1_m out)
    short* pub16   = m1b16 + (size_t)NM * HID;          // NU*64 bf16 (proj_u gather-out)
    short* pmb16   = pub16 + (size_t)NU * OUTD;         // NM*64 bf16 (proj_m gather-out)
    short* selfpu16= pmb16 + (size_t)NM * OUTD;         // NU*64 bf16 (u1@c2_u_wr + bl)
    short* selfpm16= selfpu16 + (size_t)NU * OUTD;      // NM*64 bf16 (m1@c2_m_wr + bl)
    short* wfu   = selfpm16 + (size_t)NM * OUTD;
    short* wfm   = wfu   + 8 * 1  * 512;
    short* wf1ml = wfm   + 8 * 13 * 512;
    short* wf1mr = wf1ml + 8 * 4  * 512;
    short* wf1ul = wf1mr + 8 * 4  * 512;
    short* wf1ur = wf1ul + 8 * 4  * 512;
    int* rp      = (int*)(wf1ur + 8 * 4 * 512);
    int* cursor  = rp + (N + 1);
    int* partials= cursor + N;
    int* bhist   = partials + 64;
    int* bcur    = bhist + 2 * NB;
    int* bbase   = bcur + 2 * NB;                       // 2*NB+1 entries
    int* after   = bbase + (2 * NB + 1);
    int2* stg    = (int2*)(((uintptr_t)after + 15) & ~(uintptr_t)15);  // 2E staged pairs
    int* nbr     = (int*)(stg + (size_t)2 * E);

    float* out_u = (float*)d_out;
    float* out_m = out_u + (size_t)NU * OUTD;

    // -------- weight repacks (bf16 fragments) --------
    auto repack = [&](const float* W, short* out, int K, int Ncols, int KT) {
        int total = (Ncols >> 4) * KT * 512;
        repack_w_kernel<<<(total + 255) / 256, 256, 0, stream>>>(W, out, K, Ncols, KT);
    };
    repack(enc_u_w, wfu,   16,  128, 1);
    repack(enc_m_w, wfm,   404, 128, 13);
    repack(c1_m_wl, wf1ml, 128, 128, 4);
    repack(c1_m_wr, wf1mr, 128, 128, 4);
    repack(c1_u_wl, wf1ul, 128, 128, 4);
    repack(c1_u_wr, wf1ur, 128, 128, 4);

    // -------- CSR build (fully bucketed) --------
    hipMemsetAsync(rp, 0, (size_t)(2 * N + 1 + 64 + 4 * NB) * sizeof(int), stream);
    bucket_hist_kernel<<<(E + 2047) / 2048, 256, 0, stream>>>(src, dst, bhist, BSZ_M, BSZ_U, E);
    bucket_scan_kernel<<<1, 64, 0, stream>>>(bhist, bbase);
    bucket_stage_kernel<<<(E + 2047) / 2048, 256, 0, stream>>>(
        src, dst, bbase, bcur, stg, NM, BSZ_M, BSZ_U, E);
    deg_bucket_kernel<<<2 * NB, 256, 0, stream>>>(stg, bbase, rp, NM, NU, BSZ_M, BSZ_U);
    {
        int nP = (N + 4095) / 4096;
        scan_partial_kernel<<<nP, 256, 0, stream>>>(rp, partials, N);
        scan_add_kernel<<<(N + 255) / 256, 256, 0, stream>>>(rp, partials, N, 2 * E, nP);
    }
    bucket_commit_kernel<<<2 * NB, 256, 0, stream>>>(stg, bbase, rp, cursor, nbr);

    const int mtU = NU / 16, mtM = NM / 16;      // 6250, 3125 (exact)
    const int gbU = (mtU + 3) / 4, gbM = (mtM + 3) / 4;

    // -------- encoders: MFMA, relu->LN, bf16 table out --------
    enc_mfma_kernel<8, 1><<<gbU, 256, 0, stream>>>(
        x_user, 16, (const bf16x8*)wfu, enc_u_b, enc_u_g, enc_u_be, hub16, mtU);
    enc_mfma_kernel<8, 13><<<gbM, 256, 0, stream>>>(
        x_movie, FMDIM, (const bf16x8*)wfm, enc_m_b, enc_m_g, enc_m_be, hmb16, mtM);

    // -------- layer-1: dual-side fused gather + dual MFMA + LN->relu --------
    {
        S1Args am{ (const unsigned short*)hub16, rp, 0,  nbr, (const bf16x8*)hmb16,
                   (const bf16x8*)wf1ml, (const bf16x8*)wf1mr,
                   c1_m_bl, ln1_m_g, ln1_m_b, m1b16, mtM };
        S1Args au{ (const unsigned short*)hmb16, rp, NM, nbr, (const bf16x8*)hub16,
                   (const bf16x8*)wf1ul, (const bf16x8*)wf1ur,
                   c1_u_bl, ln1_u_g, ln1_u_b, u1b16, mtU };
        sage1_dual_kernel<<<gbM + gbU, 256, 0, stream>>>(am, au, gbM);
    }

    // -------- layer-2 projections: dual-side, dual-output --------
    {
        const int gpU = (NU + 7) / 8, gpM = (NM + 7) / 8;
        PrArgs pu{ (const unsigned short*)u1b16, c2_m_wl, c2_u_wr, c2_u_bl, pub16, selfpu16, NU };
        PrArgs pm{ (const unsigned short*)m1b16, c2_u_wl, c2_m_wr, c2_m_bl, pmb16, selfpm16, NM };
        proj_dual_kernel<<<gpU + gpM, 64, 0, stream>>>(pu, pm, gpU);
    }

    // -------- final: dual-side gather64 + selfp + LN -> d_out --------
    {
        const int gfU = (NU + 7) / 8, gfM = (NM + 7) / 8;
        FnArgs fu{ (const unsigned short*)pmb16, rp, NM, nbr, (const unsigned short*)selfpu16,
                   ln2_u_g, ln2_u_b, out_u, NU };
        FnArgs fm{ (const unsigned short*)pub16, rp, 0,  nbr, (const unsigned short*)selfpm16,
                   ln2_m_g, ln2_m_b, out_m, NM };
        final_dual_kernel<<<gfU + gfM, 64, 0, stream>>>(fu, fm, gfU);
    }
}

// Round 24
// 448.619 us; speedup vs baseline: 1.1944x; 1.0696x over previous
//
#include <hip/hip_runtime.h>
#include <hip/hip_bf16.h>

#define HID 128
#define OUTD 64
#define FMDIM 404
#define NB 64
#define MAXB 2048

using bf16x8 = __attribute__((ext_vector_type(8))) short;   // 8 bf16 in 4 VGPRs
using f32x4  = __attribute__((ext_vector_type(4))) float;
using u16x8  = __attribute__((ext_vector_type(8))) unsigned short;

#define QSCALE 65536.f
#define QINV   (1.f / 65536.f)

static __device__ __forceinline__ short f2b(float f) {
    __hip_bfloat16 h = __float2bfloat16(f);          // RNE
    return *reinterpret_cast<short*>(&h);
}
static __device__ __forceinline__ float b2f(unsigned short u) {
    return __uint_as_float(((unsigned)u) << 16);
}
// fixed-point quantize for order-independent (associative) gather sums
static __device__ __forceinline__ int q16(unsigned short u) {
    return __float2int_rn(b2f(u) * QSCALE);
}

// guarded float4 load: address always in-bounds, value zero when k0+4 > Kin (Kin % 4 == 0)
static __device__ __forceinline__ float4 ld4_guard(const float* rowp, int k0, int Kin) {
    bool ok = (k0 + 4 <= Kin);
    const float4* p = reinterpret_cast<const float4*>(rowp + (ok ? k0 : 0));
    float4 v = *p;
    return ok ? v : float4{0.f, 0.f, 0.f, 0.f};
}

static __device__ __forceinline__ bf16x8 ldcvt8(const float* rowp, int k0, int Kin) {
    float4 f0 = ld4_guard(rowp, k0, Kin);
    float4 f1 = ld4_guard(rowp, k0 + 4, Kin);
    bf16x8 r;
    r[0] = f2b(f0.x); r[1] = f2b(f0.y); r[2] = f2b(f0.z); r[3] = f2b(f0.w);
    r[4] = f2b(f1.x); r[5] = f2b(f1.y); r[6] = f2b(f1.z); r[7] = f2b(f1.w);
    return r;
}

// ======================= fused weight repack: 6 segments in one launch =======================
struct RepackDesc { const float* W; short* out; int K; int Ncols; int KT; int offset; };
struct RepackAll  { RepackDesc d[6]; int grand; };

__global__ void repack_all_kernel(RepackAll ra)
{
    int idx = blockIdx.x * blockDim.x + threadIdx.x;
    if (idx >= ra.grand) return;
    int s = 0;
#pragma unroll
    for (int i = 1; i < 6; ++i) if (idx >= ra.d[i].offset) s = i;
    const RepackDesc& D = ra.d[s];
    int li = idx - D.offset;
    int j    = li & 7;
    int lane = (li >> 3) & 63;
    int grp  = li >> 9;
    int kk   = grp % D.KT, nt = grp / D.KT;
    int k    = kk * 32 + (lane >> 4) * 8 + j;
    int col  = nt * 16 + (lane & 15);
    D.out[li] = (k < D.K) ? f2b(D.W[(size_t)k * D.Ncols + col]) : (short)0;
}

// ======================= encoder MFMA body: f32 in, relu->LN, bf16 table out =======================
struct EncArgs {
    const float* A1; int Kin1;
    const bf16x8* W1;
    const float* bias; const float* g; const float* beta;
    short* outB; int mtiles;
};

template<int NT, int KT>
static __device__ __forceinline__ void enc_body(const EncArgs& E, int blk)
{
    constexpr int N = NT * 16;
    const int lane = threadIdx.x & 63;
    const int wave = threadIdx.x >> 6;
    const int t = blk * 4 + wave;
    if (t >= E.mtiles) return;

    const int lr = lane & 15;
    const int lk = lane >> 4;
    const int row = t * 16 + lr;
    const float* a1p = E.A1 + (size_t)row * E.Kin1;

    f32x4 acc[NT];
#pragma unroll
    for (int n = 0; n < NT; ++n) acc[n] = f32x4{0.f, 0.f, 0.f, 0.f};

#pragma unroll
    for (int kk = 0; kk < KT; ++kk) {
        const int k0 = kk * 32 + lk * 8;
        bf16x8 a1 = ldcvt8(a1p, k0, E.Kin1);
#pragma unroll
        for (int n = 0; n < NT; ++n) {
            bf16x8 b1 = E.W1[(size_t)(n * KT + kk) * 64 + lane];
            acc[n] = __builtin_amdgcn_mfma_f32_16x16x32_bf16(a1, b1, acc[n], 0, 0, 0);
        }
    }

    const int rowbase = t * 16;
    float v[NT][4];
#pragma unroll
    for (int n = 0; n < NT; ++n) {
        const float bc = E.bias[n * 16 + lr];
#pragma unroll
        for (int q = 0; q < 4; ++q) v[n][q] = fmaxf(acc[n][q] + bc, 0.f);
    }
    float gcol[NT], becol[NT];
#pragma unroll
    for (int n = 0; n < NT; ++n) { gcol[n] = E.g[n * 16 + lr]; becol[n] = E.beta[n * 16 + lr]; }
#pragma unroll
    for (int q = 0; q < 4; ++q) {
        float s = 0.f, ss = 0.f;
#pragma unroll
        for (int n = 0; n < NT; ++n) { s += v[n][q]; ss += v[n][q] * v[n][q]; }
#pragma unroll
        for (int m = 1; m < 16; m <<= 1) {
            s  += __shfl_xor(s, m);
            ss += __shfl_xor(ss, m);
        }
        const float mu   = s * (1.f / N);
        const float rstd = rsqrtf(ss * (1.f / N) - mu * mu + 1e-5f);
#pragma unroll
        for (int n = 0; n < NT; ++n) {
            float o = (v[n][q] - mu) * rstd * gcol[n] + becol[n];
            E.outB[(size_t)(rowbase + lk * 4 + q) * N + n * 16 + lr] = f2b(o);
        }
    }
}

// ======================= sage1 fused (dual-side launch) =======================
struct S1Args {
    const unsigned short* gfeat;
    const int* rowptr; int rowbase; const int* nbr;
    const bf16x8* A2b;
    const bf16x8* W1; const bf16x8* W2;
    const float* bias; const float* g; const float* beta;
    short* out; int mtiles;
};

static __device__ __forceinline__ void sage1_body(const S1Args& A, int t)
{
    constexpr int NT = 8, KT = 4, N = 128;
    const int lane = threadIdx.x & 63;
    const int lr = lane & 15;
    const int lk = lane >> 4;
    const int row = t * 16 + lr;

    const int beg = A.rowptr[A.rowbase + row];
    const int end = A.rowptr[A.rowbase + row + 1];
    int iacc[KT][8];
#pragma unroll
    for (int kk = 0; kk < KT; ++kk)
#pragma unroll
        for (int j = 0; j < 8; ++j) iacc[kk][j] = 0;

    for (int i = beg; i < end; ++i) {
        const int nb = A.nbr[i];
        const u16x8* rp = reinterpret_cast<const u16x8*>(A.gfeat + (size_t)nb * 128);
#pragma unroll
        for (int kk = 0; kk < KT; ++kk) {
            u16x8 vv = rp[kk * 4 + lk];
#pragma unroll
            for (int j = 0; j < 8; ++j) iacc[kk][j] += q16(vv[j]);
        }
    }
    const int cnt = end - beg;
    const float sc = ((cnt > 0) ? (1.f / (float)cnt) : 0.f) * QINV;
    bf16x8 a1f[KT];
#pragma unroll
    for (int kk = 0; kk < KT; ++kk)
#pragma unroll
        for (int j = 0; j < 8; ++j) a1f[kk][j] = f2b((float)iacc[kk][j] * sc);

    f32x4 acc[NT];
#pragma unroll
    for (int n = 0; n < NT; ++n) acc[n] = f32x4{0.f, 0.f, 0.f, 0.f};
#pragma unroll
    for (int kk = 0; kk < KT; ++kk) {
        bf16x8 a2 = A.A2b[(size_t)row * (KT * 4) + kk * 4 + lk];
#pragma unroll
        for (int n = 0; n < NT; ++n) {
            bf16x8 b1 = A.W1[(size_t)(n * KT + kk) * 64 + lane];
            acc[n] = __builtin_amdgcn_mfma_f32_16x16x32_bf16(a1f[kk], b1, acc[n], 0, 0, 0);
            bf16x8 b2 = A.W2[(size_t)(n * KT + kk) * 64 + lane];
            acc[n] = __builtin_amdgcn_mfma_f32_16x16x32_bf16(a2, b2, acc[n], 0, 0, 0);
        }
    }

    const int rowbase2 = t * 16;
    float v[NT][4];
#pragma unroll
    for (int n = 0; n < NT; ++n) {
        const float bc = A.bias[n * 16 + lr];
#pragma unroll
        for (int q = 0; q < 4; ++q) v[n][q] = acc[n][q] + bc;
    }
    float gcol[NT], becol[NT];
#pragma unroll
    for (int n = 0; n < NT; ++n) { gcol[n] = A.g[n * 16 + lr]; becol[n] = A.beta[n * 16 + lr]; }
#pragma unroll
    for (int q = 0; q < 4; ++q) {
        float s = 0.f, ss = 0.f;
#pragma unroll
        for (int n = 0; n < NT; ++n) { s += v[n][q]; ss += v[n][q] * v[n][q]; }
#pragma unroll
        for (int m = 1; m < 16; m <<= 1) {
            s  += __shfl_xor(s, m);
            ss += __shfl_xor(ss, m);
        }
        const float mu   = s * (1.f / N);
        const float rstd = rsqrtf(ss * (1.f / N) - mu * mu + 1e-5f);
#pragma unroll
        for (int n = 0; n < NT; ++n) {
            float o = fmaxf((v[n][q] - mu) * rstd * gcol[n] + becol[n], 0.f);
            A.out[(size_t)(rowbase2 + lk * 4 + q) * N + n * 16 + lr] = f2b(o);
        }
    }
}

__global__ __launch_bounds__(256) void sage1_dual_kernel(S1Args a, S1Args b, int gbA)
{
    const int blk = blockIdx.x;
    const bool isA = (blk < gbA);
    const S1Args& A = isA ? a : b;
    const int t = (isA ? blk : blk - gbA) * 4 + (int)(threadIdx.x >> 6);
    if (t >= A.mtiles) return;
    sage1_body(A, t);
}

// ======================= bucketed CSR build =======================
__global__ __launch_bounds__(256) void bucket_hist_kernel(
    const int* __restrict__ src, const int* __restrict__ dst,
    int* __restrict__ bhist, int BSZ_M, int BSZ_U, int E)
{
    __shared__ int hist[2 * NB];
    const int tid = threadIdx.x;
    const long e0 = (long)blockIdx.x * 2048;
    if (tid < 2 * NB) hist[tid] = 0;
    __syncthreads();
#pragma unroll
    for (int i = 0; i < 8; ++i) {
        long e = e0 + i * 256 + tid;
        if (e < E) {
            atomicAdd(&hist[dst[e] / BSZ_M], 1);
            atomicAdd(&hist[NB + src[e] / BSZ_U], 1);
        }
    }
    __syncthreads();
    if (tid < 2 * NB && hist[tid]) atomicAdd(&bhist[tid], hist[tid]);
}

__global__ void bucket_scan_kernel(const int* __restrict__ bhist, int* __restrict__ bbase)
{
    if (threadIdx.x == 0 && blockIdx.x == 0) {
        int run = 0;
        for (int i = 0; i < 2 * NB; ++i) { bbase[i] = run; run += bhist[i]; }
        bbase[2 * NB] = run;
    }
}

// stage body (dual-launched with enc_m)
struct StArgs {
    const int* src; const int* dst;
    const int* bbase; int* bcur;
    int2* stg; int NM; int BSZ_M; int BSZ_U; int E;
};

static __device__ __forceinline__ void stage_body(const StArgs& S, int blk)
{
    __shared__ int hist[2 * NB];
    __shared__ int basep[2 * NB];
    __shared__ int bb[2 * NB];
    const int tid = threadIdx.x;
    const long e0 = (long)blk * 2048;

    if (tid < 2 * NB) { hist[tid] = 0; bb[tid] = S.bbase[tid]; }
    __syncthreads();

    int es[8], ed[8];
#pragma unroll
    for (int i = 0; i < 8; ++i) {
        long e = e0 + i * 256 + tid;
        if (e < S.E) {
            es[i] = S.src[e]; ed[i] = S.dst[e];
            atomicAdd(&hist[ed[i] / S.BSZ_M], 1);
            atomicAdd(&hist[NB + es[i] / S.BSZ_U], 1);
        } else { es[i] = -1; ed[i] = -1; }
    }
    __syncthreads();
    if (tid < 2 * NB) {
        basep[tid] = atomicAdd(&S.bcur[tid], hist[tid]);
        hist[tid] = 0;                        // reuse as running in-block cursor
    }
    __syncthreads();
#pragma unroll
    for (int i = 0; i < 8; ++i) {
        if (ed[i] >= 0) {
            int b  = ed[i] / S.BSZ_M;
            int p  = atomicAdd(&hist[b], 1);
            S.stg[(long)bb[b] + basep[b] + p] = make_int2(ed[i], es[i]);
            int b2 = es[i] / S.BSZ_U;
            int p2 = atomicAdd(&hist[NB + b2], 1);
            S.stg[(long)bb[NB + b2] + basep[NB + b2] + p2] = make_int2(S.NM + es[i], ed[i]);
        }
    }
}

__global__ __launch_bounds__(256) void stage_encm_kernel(StArgs sa, EncArgs em, int gbA)
{
    const int blk = blockIdx.x;
    if (blk < gbA) stage_body(sa, blk);
    else           enc_body<8, 13>(em, blk - gbA);
}

// deg body (dual-launched with enc_u)
struct DgArgs {
    const int2* stg; const int* bbase;
    int* deg; int NM; int NU; int BSZ_M; int BSZ_U;
};

static __device__ __forceinline__ void deg_body(const DgArgs& D, int i)
{
    __shared__ int lh[MAXB];
    int grow, nr;
    if (i < NB) {
        int r0 = i * D.BSZ_M;
        grow = r0; nr = min(D.BSZ_M, D.NM - r0);
    } else {
        int r0 = (i - NB) * D.BSZ_U;
        grow = D.NM + r0; nr = min(D.BSZ_U, D.NU - r0);
    }
    if (nr < 0) nr = 0;
    for (int k = threadIdx.x; k < nr; k += blockDim.x) lh[k] = 0;
    __syncthreads();
    const int w0 = D.bbase[i], w1 = D.bbase[i + 1];
    for (int k = w0 + (int)threadIdx.x; k < w1; k += (int)blockDim.x) {
        int2 ent = D.stg[k];
        atomicAdd(&lh[ent.x - grow], 1);
    }
    __syncthreads();
    for (int k = threadIdx.x; k < nr; k += blockDim.x) D.deg[grow + k] = lh[k];
}

__global__ __launch_bounds__(256) void deg_encu_kernel(DgArgs da, EncArgs eu, int gbA)
{
    const int blk = blockIdx.x;
    if (blk < gbA) deg_body(da, blk);
    else           enc_body<8, 1>(eu, blk - gbA);
}

__global__ void scan_partial_kernel(int* __restrict__ data, int* __restrict__ partials, int N)
{
    __shared__ int sh[256];
    const int tid = threadIdx.x;
    const int base = blockIdx.x * 4096 + tid * 16;
    int vals[16];
    int s = 0;
#pragma unroll
    for (int i = 0; i < 16; ++i) {
        int v = (base + i < N) ? data[base + i] : 0;
        vals[i] = s;
        s += v;
    }
    sh[tid] = s;
    __syncthreads();
    for (int off = 1; off < 256; off <<= 1) {
        int t = 0;
        if (tid >= off) t = sh[tid - off];
        __syncthreads();
        sh[tid] += t;
        __syncthreads();
    }
    int excl = (tid == 0) ? 0 : sh[tid - 1];
    if (tid == 255) partials[blockIdx.x] = sh[255];
#pragma unroll
    for (int i = 0; i < 16; ++i)
        if (base + i < N) data[base + i] = excl + vals[i];
}

__global__ void scan_add_kernel(int* __restrict__ data, const int* __restrict__ partials,
                                int N, int total, int nP)
{
    __shared__ int pref[64];
    const int tid = threadIdx.x;
    if (tid < 64) {
        int v = (tid < nP) ? partials[tid] : 0;
        for (int off = 1; off < 64; off <<= 1) {
            int t = __shfl_up(v, off);
            if (tid >= off) v += t;
        }
        pref[tid] = v;                      // inclusive prefix
    }
    __syncthreads();
    int idx = blockIdx.x * blockDim.x + tid;
    if (idx < N) {
        int p = idx >> 12;
        int excl = (p == 0) ? 0 : pref[p - 1];
        data[idx] += excl;
    }
    if (idx == 0) data[N] = total;
}

__global__ __launch_bounds__(256) void bucket_commit_kernel(
    const int2* __restrict__ stg, const int* __restrict__ bbase,
    const int* __restrict__ rowptr, int* __restrict__ cursor, int* __restrict__ nbr)
{
    const int i = blockIdx.x;                 // 0 .. 2*NB-1
    const int w0 = bbase[i], w1 = bbase[i + 1];
    for (int k = w0 + (int)threadIdx.x; k < w1; k += (int)blockDim.x) {
        int2 ent = stg[k];
        int slot = rowptr[ent.x] + atomicAdd(&cursor[ent.x], 1);
        nbr[slot] = ent.y;
    }
}

// ======================= projection, dual-output, dual-side launch =======================
struct PrArgs {
    const unsigned short* feat;
    const float* wl; const float* wr; const float* bl;
    short* outp; short* outselfp; int n;
};

static __device__ __forceinline__ void proj_body(const PrArgs& A, int blk)
{
    constexpr int R = 8;
    __shared__ float4 fs[R][HID / 4];
    const int j = threadIdx.x;               // 0..63
    const int base = blk * R;

    for (int t = j; t < R * 16; t += 64) {
        int r = t >> 4, k = t & 15;
        int row = base + r;
        if (row < A.n) {
            u16x8 v = *(const u16x8*)(A.feat + (size_t)row * HID + k * 8);
            fs[r][2 * k]     = float4{b2f(v[0]), b2f(v[1]), b2f(v[2]), b2f(v[3])};
            fs[r][2 * k + 1] = float4{b2f(v[4]), b2f(v[5]), b2f(v[6]), b2f(v[7])};
        }
    }
    __syncthreads();

    const float blj = A.bl[j];
    float accP[R], accS[R];
#pragma unroll
    for (int r = 0; r < R; ++r) { accP[r] = 0.f; accS[r] = blj; }

    for (int k4 = 0; k4 < 32; ++k4) {
        const float* wp = A.wl + (size_t)(4 * k4) * OUTD + j;
        const float* wq = A.wr + (size_t)(4 * k4) * OUTD + j;
        float p0 = wp[0 * OUTD], p1 = wp[1 * OUTD], p2 = wp[2 * OUTD], p3 = wp[3 * OUTD];
        float q0 = wq[0 * OUTD], q1 = wq[1 * OUTD], q2 = wq[2 * OUTD], q3 = wq[3 * OUTD];
#pragma unroll
        for (int r = 0; r < R; ++r) {
            float4 v = fs[r][k4];
            accP[r] = fmaf(v.x, p0, accP[r]);
            accP[r] = fmaf(v.y, p1, accP[r]);
            accP[r] = fmaf(v.z, p2, accP[r]);
            accP[r] = fmaf(v.w, p3, accP[r]);
            accS[r] = fmaf(v.x, q0, accS[r]);
            accS[r] = fmaf(v.y, q1, accS[r]);
            accS[r] = fmaf(v.z, q2, accS[r]);
            accS[r] = fmaf(v.w, q3, accS[r]);
        }
    }
    for (int r = 0; r < R; ++r) {
        int row = base + r;
        if (row < A.n) {
            A.outp[(size_t)row * OUTD + j]     = f2b(accP[r]);
            A.outselfp[(size_t)row * OUTD + j] = f2b(accS[r]);
        }
    }
}

__global__ __launch_bounds__(64) void proj_dual_kernel(PrArgs a, PrArgs b, int gbA)
{
    const int blk = blockIdx.x;
    if (blk < gbA) proj_body(a, blk);
    else           proj_body(b, blk - gbA);
}

// ======================= final fused, dual-side launch =======================
struct FnArgs {
    const unsigned short* pfeat;
    const int* rowptr; int rowbase; const int* nbr;
    const unsigned short* selfp;
    const float* g; const float* beta;
    float* out; int n;
};

static __device__ __forceinline__ void final_body(const FnArgs& A, int blk)
{
    constexpr int R = 8;
    const int j = threadIdx.x;               // 0..63
    const int base = blk * R;

    const float gv = A.g[j], bv = A.beta[j];
#pragma unroll
    for (int r = 0; r < R; ++r) {
        int row = base + r;
        float v = 0.f;
        if (row < A.n) {
            const int beg = A.rowptr[A.rowbase + row];
            const int end = A.rowptr[A.rowbase + row + 1];
            int s0 = 0, s1 = 0, s2 = 0, s3 = 0, s4 = 0, s5 = 0, s6 = 0, s7 = 0;
            int i = beg;
            for (; i + 7 < end; i += 8) {
                int n0 = A.nbr[i],     n1 = A.nbr[i + 1], n2 = A.nbr[i + 2], n3 = A.nbr[i + 3];
                int n4 = A.nbr[i + 4], n5 = A.nbr[i + 5], n6 = A.nbr[i + 6], n7 = A.nbr[i + 7];
                s0 += q16(A.pfeat[(size_t)n0 * OUTD + j]);
                s1 += q16(A.pfeat[(size_t)n1 * OUTD + j]);
                s2 += q16(A.pfeat[(size_t)n2 * OUTD + j]);
                s3 += q16(A.pfeat[(size_t)n3 * OUTD + j]);
                s4 += q16(A.pfeat[(size_t)n4 * OUTD + j]);
                s5 += q16(A.pfeat[(size_t)n5 * OUTD + j]);
                s6 += q16(A.pfeat[(size_t)n6 * OUTD + j]);
                s7 += q16(A.pfeat[(size_t)n7 * OUTD + j]);
            }
            for (; i + 3 < end; i += 4) {
                int n0 = A.nbr[i], n1 = A.nbr[i + 1], n2 = A.nbr[i + 2], n3 = A.nbr[i + 3];
                s0 += q16(A.pfeat[(size_t)n0 * OUTD + j]);
                s1 += q16(A.pfeat[(size_t)n1 * OUTD + j]);
                s2 += q16(A.pfeat[(size_t)n2 * OUTD + j]);
                s3 += q16(A.pfeat[(size_t)n3 * OUTD + j]);
            }
            for (; i < end; ++i)
                s0 += q16(A.pfeat[(size_t)A.nbr[i] * OUTD + j]);
            int isum = ((s0 + s1) + (s2 + s3)) + ((s4 + s5) + (s6 + s7));
            const int cnt = end - beg;
            const float sc = ((cnt > 0) ? (1.f / (float)cnt) : 0.f) * QINV;
            v = (float)isum * sc + b2f(A.selfp[(size_t)row * OUTD + j]);
        }
        float s = v, q = v * v;
        for (int o = 32; o > 0; o >>= 1) { s += __shfl_down(s, o); q += __shfl_down(q, o); }
        s = __shfl(s, 0); q = __shfl(q, 0);
        float mu = s * (1.f / OUTD);
        float rstd = rsqrtf(q * (1.f / OUTD) - mu * mu + 1e-5f);
        if (row < A.n) A.out[(size_t)row * OUTD + j] = (v - mu) * rstd * gv + bv;
    }
}

__global__ __launch_bounds__(64) void final_dual_kernel(FnArgs a, FnArgs b, int gbA)
{
    const int blk = blockIdx.x;
    if (blk < gbA) final_body(a, blk);
    else           final_body(b, blk - gbA);
}

extern "C" void kernel_launch(void* const* d_in, const int* in_sizes, int n_in,
                              void* d_out, int out_size, void* d_ws, size_t ws_size,
                              hipStream_t stream)
{
    const float* x_user   = (const float*)d_in[0];
    const float* x_movie  = (const float*)d_in[1];
    const int*   src      = (const int*)d_in[2];
    const int*   dst      = (const int*)d_in[3];
    const float* enc_u_w  = (const float*)d_in[4];
    const float* enc_u_b  = (const float*)d_in[5];
    const float* enc_u_g  = (const float*)d_in[6];
    const float* enc_u_be = (const float*)d_in[7];
    const float* enc_m_w  = (const float*)d_in[8];
    const float* enc_m_b  = (const float*)d_in[9];
    const float* enc_m_g  = (const float*)d_in[10];
    const float* enc_m_be = (const float*)d_in[11];
    const float* c1_m_wl  = (const float*)d_in[12];
    const float* c1_m_bl  = (const float*)d_in[13];
    const float* c1_m_wr  = (const float*)d_in[14];
    const float* c1_u_wl  = (const float*)d_in[15];
    const float* c1_u_bl  = (const float*)d_in[16];
    const float* c1_u_wr  = (const float*)d_in[17];
    const float* ln1_u_g  = (const float*)d_in[18];
    const float* ln1_u_b  = (const float*)d_in[19];
    const float* ln1_m_g  = (const float*)d_in[20];
    const float* ln1_m_b  = (const float*)d_in[21];
    const float* c2_m_wl  = (const float*)d_in[22];
    const float* c2_m_bl  = (const float*)d_in[23];
    const float* c2_m_wr  = (const float*)d_in[24];
    const float* c2_u_wl  = (const float*)d_in[25];
    const float* c2_u_bl  = (const float*)d_in[26];
    const float* c2_u_wr  = (const float*)d_in[27];
    const float* ln2_u_g  = (const float*)d_in[28];
    const float* ln2_u_b  = (const float*)d_in[29];
    const float* ln2_m_g  = (const float*)d_in[30];
    const float* ln2_m_b  = (const float*)d_in[31];

    const int NU = in_sizes[0] / 16;
    const int NM = in_sizes[1] / FMDIM;
    const int E  = in_sizes[2];
    const int N  = NM + NU;
    const int BSZ_M = (NM + NB - 1) / NB;
    const int BSZ_U = (NU + NB - 1) / NB;

    // -------- workspace layout (all bf16 tables; no overlays) --------
    short* hub16   = (short*)d_ws;                      // NU*128 bf16 (enc_u out)
    short* hmb16   = hub16 + (size_t)NU * HID;          // NM*128 bf16 (enc_m out)
    short* u1b16   = hmb16 + (size_t)NM * HID;          // NU*128 bf16 (sage1_u out)
    short* m1b16   = u1b16 + (size_t)NU * HID;          // NM*128 bf16 (sage1_m out)
    short* pub16   = m1b16 + (size_t)NM * HID;          // NU*64 bf16 (proj_u gather-out)
    short* pmb16   = pub16 + (size_t)NU * OUTD;         // NM*64 bf16 (proj_m gather-out)
    short* selfpu16= pmb16 + (size_t)NM * OUTD;         // NU*64 bf16 (u1@c2_u_wr + bl)
    short* selfpm16= selfpu16 + (size_t)NU * OUTD;      // NM*64 bf16 (m1@c2_m_wr + bl)
    short* wfu   = selfpm16 + (size_t)NM * OUTD;
    short* wfm   = wfu   + 8 * 1  * 512;
    short* wf1ml = wfm   + 8 * 13 * 512;
    short* wf1mr = wf1ml + 8 * 4  * 512;
    short* wf1ul = wf1mr + 8 * 4  * 512;
    short* wf1ur = wf1ul + 8 * 4  * 512;
    int* rp      = (int*)(wf1ur + 8 * 4 * 512);
    int* cursor  = rp + (N + 1);
    int* partials= cursor + N;
    int* bhist   = partials + 64;
    int* bcur    = bhist + 2 * NB;
    int* bbase   = bcur + 2 * NB;                       // 2*NB+1 entries
    int* after   = bbase + (2 * NB + 1);
    int2* stg    = (int2*)(((uintptr_t)after + 15) & ~(uintptr_t)15);  // 2E staged pairs
    int* nbr     = (int*)(stg + (size_t)2 * E);

    float* out_u = (float*)d_out;
    float* out_m = out_u + (size_t)NU * OUTD;

    // -------- fused weight repack (1 launch, 6 segments) --------
    {
        RepackAll ra;
        int off = 0;
        auto seg = [&](int i, const float* W, short* out, int K, int Ncols, int KT) {
            ra.d[i] = RepackDesc{ W, out, K, Ncols, KT, off };
            off += (Ncols >> 4) * KT * 512;
        };
        seg(0, enc_u_w, wfu,   16,  128, 1);
        seg(1, enc_m_w, wfm,   404, 128, 13);
        seg(2, c1_m_wl, wf1ml, 128, 128, 4);
        seg(3, c1_m_wr, wf1mr, 128, 128, 4);
        seg(4, c1_u_wl, wf1ul, 128, 128, 4);
        seg(5, c1_u_wr, wf1ur, 128, 128, 4);
        ra.grand = off;
        repack_all_kernel<<<(off + 255) / 256, 256, 0, stream>>>(ra);
    }

    // -------- CSR build interleaved with encoders (dual launches) --------
    hipMemsetAsync(rp, 0, (size_t)(2 * N + 1 + 64 + 4 * NB) * sizeof(int), stream);
    bucket_hist_kernel<<<(E + 2047) / 2048, 256, 0, stream>>>(src, dst, bhist, BSZ_M, BSZ_U, E);
    bucket_scan_kernel<<<1, 64, 0, stream>>>(bhist, bbase);

    const int mtU = NU / 16, mtM = NM / 16;      // 6250, 3125 (exact)
    const int gbU = (mtU + 3) / 4, gbM = (mtM + 3) / 4;
    const int gbStage = (E + 2047) / 2048;

    {   // stage ∥ enc_m
        StArgs sa{ src, dst, bbase, bcur, stg, NM, BSZ_M, BSZ_U, E };
        EncArgs em{ x_movie, FMDIM, (const bf16x8*)wfm, enc_m_b, enc_m_g, enc_m_be, hmb16, mtM };
        stage_encm_kernel<<<gbStage + gbM, 256, 0, stream>>>(sa, em, gbStage);
    }
    {   // deg ∥ enc_u
        DgArgs da{ stg, bbase, rp, NM, NU, BSZ_M, BSZ_U };
        EncArgs eu{ x_user, 16, (const bf16x8*)wfu, enc_u_b, enc_u_g, enc_u_be, hub16, mtU };
        deg_encu_kernel<<<2 * NB + gbU, 256, 0, stream>>>(da, eu, 2 * NB);
    }
    {
        int nP = (N + 4095) / 4096;
        scan_partial_kernel<<<nP, 256, 0, stream>>>(rp, partials, N);
        scan_add_kernel<<<(N + 255) / 256, 256, 0, stream>>>(rp, partials, N, 2 * E, nP);
    }
    bucket_commit_kernel<<<2 * NB, 256, 0, stream>>>(stg, bbase, rp, cursor, nbr);

    // -------- layer-1: dual-side fused gather + dual MFMA + LN->relu --------
    {
        S1Args am{ (const unsigned short*)hub16, rp, 0,  nbr, (const bf16x8*)hmb16,
                   (const bf16x8*)wf1ml, (const bf16x8*)wf1mr,
                   c1_m_bl, ln1_m_g, ln1_m_b, m1b16, mtM };
        S1Args au{ (const unsigned short*)hmb16, rp, NM, nbr, (const bf16x8*)hub16,
                   (const bf16x8*)wf1ul, (const bf16x8*)wf1ur,
                   c1_u_bl, ln1_u_g, ln1_u_b, u1b16, mtU };
        sage1_dual_kernel<<<gbM + gbU, 256, 0, stream>>>(am, au, gbM);
    }

    // -------- layer-2 projections: dual-side, dual-output --------
    {
        const int gpU = (NU + 7) / 8, gpM = (NM + 7) / 8;
        PrArgs pu{ (const unsigned short*)u1b16, c2_m_wl, c2_u_wr, c2_u_bl, pub16, selfpu16, NU };
        PrArgs pm{ (const unsigned short*)m1b16, c2_u_wl, c2_m_wr, c2_m_bl, pmb16, selfpm16, NM };
        proj_dual_kernel<<<gpU + gpM, 64, 0, stream>>>(pu, pm, gpU);
    }

    // -------- final: dual-side gather64 + selfp + LN -> d_out --------
    {
        const int gfU = (NU + 7) / 8, gfM = (NM + 7) / 8;
        FnArgs fu{ (const unsigned short*)pmb16, rp, NM, nbr, (const unsigned short*)selfpu16,
                   ln2_u_g, ln2_u_b, out_u, NU };
        FnArgs fm{ (const unsigned short*)pub16, rp, 0,  nbr, (const unsigned short*)selfpm16,
                   ln2_m_g, ln2_m_b, out_m, NM };
        final_dual_kernel<<<gfU + gfM, 64, 0, stream>>>(fu, fm, gfU);
    }
}